// Round 2
// baseline (140.254 us; speedup 1.0000x reference)
//
#include <hip/hip_runtime.h>
#include <math.h>

#define PI_F 3.14159265358979323846f
#define NB 8
#define NH 128
#define NL 4096
#define LF 2049    // NL/2 + 1
#define WB 2064    // padded per-batch column width (>=2049, mult of 16)
#define NT 16512   // WB * NB = total GEMM columns (= 258 * 64)

typedef float2 cpx;
typedef __attribute__((ext_vector_type(8))) short bf8v;   // 8 bf16 in 4 VGPRs
typedef __attribute__((ext_vector_type(4))) float f4;     // MFMA acc

#define MFMA16(a, b, c) __builtin_amdgcn_mfma_f32_16x16x32_bf16(a, b, c, 0, 0, 0)

__device__ __forceinline__ float gelu_exact(float x) {
  return 0.5f * x * (1.0f + erff(x * 0.70710678118654752f));
}
__device__ __forceinline__ unsigned short f2bf(float f) {
  unsigned int x = __float_as_uint(f);
  return (unsigned short)((x + 0x7FFFu + ((x >> 16) & 1u)) >> 16);
}
__device__ __forceinline__ float bf2f(unsigned short h) {
  return __uint_as_float((unsigned int)h << 16);
}
__device__ __forceinline__ unsigned int packpair(float re, float im) {
  return (unsigned int)f2bf(re) | ((unsigned int)f2bf(im) << 16);
}
__device__ __forceinline__ cpx cadd(cpx a, cpx b) { return make_float2(a.x + b.x, a.y + b.y); }
__device__ __forceinline__ cpx csub(cpx a, cpx b) { return make_float2(a.x - b.x, a.y - b.y); }
__device__ __forceinline__ cpx cmul(cpx a, cpx b) {
  return make_float2(fmaf(a.x, b.x, -a.y * b.y), fmaf(a.x, b.y, a.y * b.x));
}
template <int SGN>
__device__ __forceinline__ cpx mulJ(cpx a) {
  return (SGN < 0) ? make_float2(a.y, -a.x) : make_float2(-a.y, a.x);
}

// Pre-swizzled global layout for Mb/Mc: tile = k>>5 (256 rows x 32 k per tile,
// 8192 shorts), slot = m*4 + ((k>>3 & 3) ^ (m & 3)), elem = k&7.  Makes the
// GEMM A-staging a LINEAR copy (global_load_lds) with the XOR-swizzle baked
// into the source (both-sides-or-neither rule).
__device__ __forceinline__ void wrM(unsigned short* __restrict__ H,
                                    unsigned short* __restrict__ L,
                                    int m, int k, float v) {
  size_t a = (size_t)(k >> 5) * 8192 +
             (size_t)(m * 4 + (((k >> 3) & 3) ^ (m & 3))) * 8 + (k & 7);
  unsigned short h = f2bf(v);
  H[a] = h;
  L[a] = f2bf(v - bf2f(h));
}

// async global->LDS, 16B per lane; LDS dest is wave-uniform base + lane*16.
__device__ __forceinline__ void gload16(const unsigned short* g, unsigned short* l) {
  __builtin_amdgcn_global_load_lds(
      (const __attribute__((address_space(1))) unsigned int*)g,
      (__attribute__((address_space(3))) unsigned int*)l, 16, 0, 0);
}

// ---------------- register FFT-2048: radix 8*8*8*4, 256 threads ----------------
#define SW(k) ((k) ^ (((k) >> 4) & 31))

template <int SGN>
__device__ __forceinline__ void dft8(cpx a[8]) {
  cpx t0 = cadd(a[0], a[4]), u0 = csub(a[0], a[4]);
  cpx t1 = cadd(a[1], a[5]), u1 = csub(a[1], a[5]);
  cpx t2 = cadd(a[2], a[6]), u2 = csub(a[2], a[6]);
  cpx t3 = cadd(a[3], a[7]), u3 = csub(a[3], a[7]);
  cpx E0 = cadd(t0, t2), E2 = csub(t0, t2);
  cpx ju2 = mulJ<SGN>(u2);
  cpx E1 = cadd(u0, ju2), E3 = csub(u0, ju2);
  cpx O0 = cadd(t1, t3), O2 = csub(t1, t3);
  cpx ju3 = mulJ<SGN>(u3);
  cpx O1 = cadd(u1, ju3), O3 = csub(u1, ju3);
  const float r = 0.70710678118654752f;
  const float S = (float)SGN;
  cpx w1O1 = make_float2(r * (O1.x - S * O1.y), r * (O1.y + S * O1.x));
  cpx w3O3 = make_float2(r * (-O3.x - S * O3.y), r * (S * O3.x - O3.y));
  cpx jO2 = mulJ<SGN>(O2);
  a[0] = cadd(E0, O0);   a[4] = csub(E0, O0);
  a[1] = cadd(E1, w1O1); a[5] = csub(E1, w1O1);
  a[2] = cadd(E2, jO2);  a[6] = csub(E2, jO2);
  a[3] = cadd(E3, w3O3); a[7] = csub(E3, w3O3);
}

template <int SGN>
__device__ __forceinline__ void dft4(cpx b[4]) {
  cpx s0 = cadd(b[0], b[2]), d0 = csub(b[0], b[2]);
  cpx s1 = cadd(b[1], b[3]), d1 = csub(b[1], b[3]);
  cpx jd1 = mulJ<SGN>(d1);
  b[0] = cadd(s0, s1); b[2] = csub(s0, s1);
  b[1] = cadd(d0, jd1); b[3] = csub(d0, jd1);
}

__device__ __forceinline__ void twid8(cpx a[8], float ang) {
  float s, c; __sincosf(ang, &s, &c);
  cpx w1 = make_float2(c, s);
  cpx w2 = cmul(w1, w1), w3 = cmul(w2, w1), w4 = cmul(w2, w2);
  cpx w5 = cmul(w3, w2), w6 = cmul(w3, w3), w7 = cmul(w4, w3);
  a[1] = cmul(a[1], w1); a[2] = cmul(a[2], w2); a[3] = cmul(a[3], w3);
  a[4] = cmul(a[4], w4); a[5] = cmul(a[5], w5); a[6] = cmul(a[6], w6);
  a[7] = cmul(a[7], w7);
}

template <int SGN>
__device__ __forceinline__ void fft2048_core(cpx a[8], cpx* __restrict__ bufA,
                                             cpx* __restrict__ bufB, int t) {
  const float S = (float)SGN;
  dft8<SGN>(a);
  twid8(a, S * (2.f * PI_F / 2048.f) * (float)t);
#pragma unroll
  for (int p = 0; p < 8; ++p) bufA[p * 264 + t] = a[p];
  __syncthreads();
  int p = t >> 5, n1 = t & 31;
#pragma unroll
  for (int j = 0; j < 8; ++j) a[j] = bufA[p * 264 + n1 + 32 * j];
  dft8<SGN>(a);
  twid8(a, S * (2.f * PI_F / 256.f) * (float)n1);
#pragma unroll
  for (int q = 0; q < 8; ++q) bufB[p * 264 + q * 33 + n1] = a[q];
  __syncthreads();
  int q = (t >> 2) & 7, n2 = t & 3;
#pragma unroll
  for (int j = 0; j < 8; ++j) a[j] = bufB[p * 264 + q * 33 + n2 + 4 * j];
  dft8<SGN>(a);
  twid8(a, S * (2.f * PI_F / 32.f) * (float)n2);
#pragma unroll
  for (int d = 0; d < 8; ++d) bufA[p * 264 + q * 33 + 4 * d + n2] = a[d];
  __syncthreads();
#pragma unroll
  for (int h = 0; h < 2; ++h) {
    int d = 2 * n2 + h;
    cpx b[4];
#pragma unroll
    for (int m = 0; m < 4; ++m) b[m] = bufA[p * 264 + q * 33 + 4 * d + m];
    dft4<SGN>(b);
    int kb = p + 8 * q + 64 * d;
#pragma unroll
    for (int c = 0; c < 4; ++c) bufB[SW(kb + 512 * c)] = b[c];
  }
  __syncthreads();
}

// ---------------- fused: precomp (blocks 0..191) + forward rfft-4096 pack ----------------
// Precomp operands now staged through LDS (one coalesced/vector load instead of
// 128 serialized wave-uniform loads) so the precomp blocks don't tail the FFT wave.
__global__ __launch_bounds__(256) void fwd_pre(
    const float* __restrict__ u,
    const float* __restrict__ C2, const float* __restrict__ B2,
    const float* __restrict__ D,
    unsigned int* __restrict__ Uph,
    unsigned short* __restrict__ Mbh, unsigned short* __restrict__ Mbl,
    unsigned short* __restrict__ Mch, unsigned short* __restrict__ Mcl) {
  __shared__ cpx bufA[2112], bufB[2112];
  int t = threadIdx.x;
  if (blockIdx.x < 192) {
    __shared__ float rc[128], rs[128];
    __shared__ float sOr[2][128], sOi[2][128];
    __shared__ float sTr[2][128], sTi[2][128];
    int e = blockIdx.x;
    int which = e >> 6;                 // 0: Mb, 1: C~, 2: D~ (uniform per block)
    int half = t >> 7, tt = t & 127;
    int x = (2 * e + half) & 127;
    { float s, c; sincosf(-(2.f * PI_F / 128.f) * (float)tt, &s, &c); rc[tt] = c; rs[tt] = s; }
    if (which == 0) {   // stage B~ source row x: B2[x*128 + k]
      float2 v = ((const float2*)B2)[(size_t)x * 128 + tt];
      sOr[half][tt] = v.x; sOi[half][tt] = v.y;
    } else if (which == 1) {  // stage C~ source column x: C2[k*128 + x]
      float2 v = ((const float2*)C2)[(size_t)tt * 128 + x];
      sOr[half][tt] = v.x; sOi[half][tt] = v.y;
    }
    __syncthreads();
    float sr = 0.f, si = 0.f;
    if (which == 0) {
      // B~[p=x][q=tt]
#pragma unroll 4
      for (int k = 0; k < 128; ++k) {
        int j = (k * tt) & 127; float c = rc[j], s = rs[j];
        float br = sOr[half][k], bi = sOi[half][k];
        sr += br * c - bi * s; si += br * s + bi * c;
      }
      wrM(Mbh, Mbl, 2 * x,     2 * tt,     sr);
      wrM(Mbh, Mbl, 2 * x,     2 * tt + 1, -si);
      wrM(Mbh, Mbl, 2 * x + 1, 2 * tt,     si);
      wrM(Mbh, Mbl, 2 * x + 1, 2 * tt + 1,  sr);
    } else if (which == 1) {
      // C~[h=tt][p=x] (scaled by 1/128)
#pragma unroll 4
      for (int k = 0; k < 128; ++k) {
        int j = (k * tt) & 127; float c = rc[j], s = -rs[j];  // e^{+i theta}
        float cr = sOr[half][k], ci = sOi[half][k];
        sr += cr * c - ci * s; si += cr * s + ci * c;
      }
      sr *= (1.f / 128.f); si *= (1.f / 128.f);
      wrM(Mch, Mcl, 2 * tt,     2 * x,     sr);
      wrM(Mch, Mcl, 2 * tt,     2 * x + 1, -si);
      wrM(Mch, Mcl, 2 * tt + 1, 2 * x,     si);
      wrM(Mch, Mcl, 2 * tt + 1, 2 * x + 1,  sr);
    } else {
      // phase 1: T[tt][x] = sum_k D[tt][k] e^{-2pi i k x/128}  (row read, unrolled
      // so the per-thread loads pipeline)
#pragma unroll 8
      for (int k = 0; k < 128; ++k) {
        int j = (k * x) & 127; float c = rc[j], s = rs[j];
        float d = D[tt * 128 + k];
        sr += d * c; si += d * s;
      }
      sTr[half][tt] = sr; sTi[half][tt] = si;
      __syncthreads();
      // phase 2: D~[h=tt][q=x] = (1/128) sum_k e^{+2pi i k tt/128} T[k][x]
      sr = 0.f; si = 0.f;
#pragma unroll 4
      for (int k = 0; k < 128; ++k) {
        int j = (k * tt) & 127; float c = rc[j], s = -rs[j];
        sr += sTr[half][k] * c - sTi[half][k] * s;
        si += sTr[half][k] * s + sTi[half][k] * c;
      }
      sr *= (1.f / 128.f); si *= (1.f / 128.f);
      wrM(Mch, Mcl, 2 * tt,     256 + 2 * x,     sr);
      wrM(Mch, Mcl, 2 * tt,     256 + 2 * x + 1, -si);
      wrM(Mch, Mcl, 2 * tt + 1, 256 + 2 * x,     si);
      wrM(Mch, Mcl, 2 * tt + 1, 256 + 2 * x + 1,  sr);
    }
    return;
  }
  int row = blockIdx.x - 192;
  int b = row >> 7, q = row & 127;
  const cpx* src = (const cpx*)(u + (size_t)row * NL);
  cpx a[8];
#pragma unroll
  for (int j = 0; j < 8; ++j) a[j] = src[t + 256 * j];
  fft2048_core<-1>(a, bufA, bufB, t);
  unsigned int* Uh = Uph + (size_t)q * NT + (size_t)b * WB;
  auto pstore = [&](int k, float ur, float ui) { Uh[k] = packpair(ur, ui); };
#pragma unroll
  for (int r = 0; r < 4; ++r) {
    int k = t + (r << 8);
    if (k == 0) {
      cpx z0 = bufB[SW(0)];
      pstore(0, z0.x + z0.y, 0.f);
      pstore(2048, z0.x - z0.y, 0.f);
      cpx zN = bufB[SW(1024)];
      pstore(1024, zN.x, -zN.y);
    } else {
      cpx A = bufB[SW(k)];
      cpx M = bufB[SW(2048 - k)];
      float Br = M.x, Bi = -M.y;
      float sr = 0.5f * (A.x + Br), si = 0.5f * (A.y + Bi);
      float dr = 0.5f * (A.x - Br), di = 0.5f * (A.y - Bi);
      float th = (float)k * (PI_F / 2048.f);
      float sn, cs; __sincosf(th, &sn, &cs);
      float tr = cs * dr + sn * di;
      float ti = cs * di - sn * dr;
      pstore(k, sr + ti, si - tr);
      float A2r = M.x, A2i = M.y;
      float B2r = A.x, B2i = -A.y;
      float s2r = 0.5f * (A2r + B2r), s2i = 0.5f * (A2i + B2i);
      float d2r = 0.5f * (A2r - B2r), d2i = 0.5f * (A2i - B2i);
      float t2r = -cs * d2r + sn * d2i;
      float t2i = -cs * d2i - sn * d2r;
      pstore(2048 - k, s2r + t2i, s2i - t2r);
    }
  }
}

// ---------------- fused GEMM: V = k.(Mb U), Y = Mc [V; U] ----------------
// Barrier-free K-loops; A double-buffered via global_load_lds (wave-private
// quarter); B in a depth-3 register ring (prefetch 2 iters ahead -> steady
// vmcnt(40), never 0 mid-loop).  Single raw s_barrier for the V handoff
// (producer lgkmcnt(0) first) -- avoids the __syncthreads vmcnt(0) drain of
// the phase-2 A prefetch.
__global__ __launch_bounds__(256, 1) void gemm_fused(
    const unsigned short* __restrict__ Mbh, const unsigned short* __restrict__ Mbl,
    const unsigned short* __restrict__ Mch, const unsigned short* __restrict__ Mcl,
    const unsigned int* __restrict__ Uph,
    const float* __restrict__ Lam,
    float2* __restrict__ Yp) {
  __shared__ unsigned short Ah[2][8192], Al[2][8192];  // 2 x (256 rows x 32 k), slot-swizzled
  __shared__ unsigned int Vl[8448];                    // 32 chunks x 264 dwords (bank-spread)
  int tid = threadIdx.x;
  int j0 = blockIdx.x * 64;
  int w = tid >> 6, lane = tid & 63, quad = lane >> 4, ln = lane & 15;

  unsigned int breg[3][4][4];
  f4 acc[4][4];

#define STAGE_A(H, L, tile, buf)                                              \
  {                                                                           \
    size_t tb_ = (size_t)(tile) * 8192;                                       \
    _Pragma("unroll") for (int r_ = 0; r_ < 4; ++r_) {                        \
      int sb_ = w * 256 + r_ * 64;                                            \
      gload16((H) + tb_ + (size_t)(sb_ + lane) * 8, &Ah[buf][sb_ * 8]);       \
      gload16((L) + tb_ + (size_t)(sb_ + lane) * 8, &Al[buf][sb_ * 8]);       \
    }                                                                         \
  }
#define LOAD_B(g, it)                                                         \
  {                                                                           \
    _Pragma("unroll") for (int nt_ = 0; nt_ < 4; ++nt_)                       \
      _Pragma("unroll") for (int c_ = 0; c_ < 4; ++c_)                        \
        breg[g][nt_][c_] =                                                    \
            Uph[(size_t)((it) * 16 + quad * 4 + c_) * NT + j0 + nt_ * 16 + ln]; \
  }
#define VMW(n) asm volatile("s_waitcnt vmcnt(" #n ")" ::: "memory")
#define LGW()  asm volatile("s_waitcnt lgkmcnt(0)" ::: "memory")

  auto bFromReg = [&](int g, bf8v bh[4]) {
#pragma unroll
    for (int nt = 0; nt < 4; ++nt) {
      union { unsigned int u[4]; bf8v v; } cv;
#pragma unroll
      for (int c = 0; c < 4; ++c) cv.u[c] = breg[g][nt][c];
      bh[nt] = cv.v;
    }
  };
  auto bFromV = [&](int i, bf8v bh[4]) {
    const unsigned short* Vs = (const unsigned short*)Vl;
#pragma unroll
    for (int nt = 0; nt < 4; ++nt)
      bh[nt] = *(const bf8v*)&Vs[(size_t)(i * 4 + quad) * 528 + (nt * 16 + ln) * 8];
  };
  auto compute = [&](int buf, const bf8v* bh) {
    bf8v ah[4], al[4];
#pragma unroll
    for (int mt = 0; mt < 4; ++mt) {
      int m = w * 64 + mt * 16 + ln;
      int off = (m * 4 + (quad ^ (m & 3))) * 8;
      ah[mt] = *(const bf8v*)&Ah[buf][off];
      al[mt] = *(const bf8v*)&Al[buf][off];
    }
#pragma unroll
    for (int mt = 0; mt < 4; ++mt)
#pragma unroll
      for (int nt = 0; nt < 4; ++nt) {
        acc[mt][nt] = MFMA16(ah[mt], bh[nt], acc[mt][nt]);
        acc[mt][nt] = MFMA16(al[mt], bh[nt], acc[mt][nt]);
      }
  };

  // ---- phase 1: V2(256 x 64) = Mb x U2 ----
  // outstanding-vmem ledger (per wave): A tile = 8 gloads, B tile = 16 loads.
  STAGE_A(Mbh, Mbl, 0, 0);     // A0: 8
  LOAD_B(0, 0);                // B0: 24
  LOAD_B(1, 1);                // B1: 40
#pragma unroll
  for (int mt = 0; mt < 4; ++mt)
#pragma unroll
    for (int nt = 0; nt < 4; ++nt) acc[mt][nt] = (f4){0.f, 0.f, 0.f, 0.f};

#pragma unroll
  for (int i = 0; i < 6; ++i) {
    LGW();                                   // prev compute's ds_reads done
    STAGE_A(Mbh, Mbl, i + 1, (i + 1) & 1);   // +8
    LOAD_B((i + 2) % 3, i + 2);              // +16 -> 64 in flight max
    VMW(40);                                 // A(i),B(i) landed; B(i+1),A(i+1),B(i+2) in flight
    bf8v bh[4]; bFromReg(i % 3, bh); compute(i & 1, bh);
  }
  { // i = 6 (no more phase-1 B to prefetch)
    LGW(); STAGE_A(Mbh, Mbl, 7, 1); VMW(24);   // A6 landed; B7,A7 in flight
    bf8v bh[4]; bFromReg(0, bh); compute(0, bh);
  }
  { // i = 7: also prefetch phase-2 A tile 0 into slot 0 (freed by compute(6))
    LGW(); STAGE_A(Mch, Mcl, 0, 0); VMW(8);    // A7,B7 landed; Ac0 in flight
    bf8v bh[4]; bFromReg(1, bh); compute(1, bh);
  }

  // phase-1 epilogue: Cauchy scale, V -> LDS
#pragma unroll
  for (int mt = 0; mt < 4; ++mt) {
    int r0 = w * 64 + mt * 16 + quad * 4;
    int p0 = r0 >> 1;   // even
    float2 lam0 = ((const float2*)Lam)[p0];
    float2 lam1 = ((const float2*)Lam)[p0 + 1];
#pragma unroll
    for (int nt = 0; nt < 4; ++nt) {
      int col = nt * 16 + ln;
      int gcol = j0 + col;
      int bb = gcol / WB; int l = gcol - bb * WB;
      float omega = (float)l * (PI_F / 2048.f);
      f4 a = acc[mt][nt];
      float dx0 = -lam0.x, dy0 = omega - lam0.y;
      float inv0 = 1.f / (dx0 * dx0 + dy0 * dy0);
      float kr0 = dx0 * inv0, ki0 = -dy0 * inv0;
      float v0r = kr0 * a[0] - ki0 * a[1];
      float v0i = kr0 * a[1] + ki0 * a[0];
      float dx1 = -lam1.x, dy1 = omega - lam1.y;
      float inv1 = 1.f / (dx1 * dx1 + dy1 * dy1);
      float kr1 = dx1 * inv1, ki1 = -dy1 * inv1;
      float v1r = kr1 * a[2] - ki1 * a[3];
      float v1i = kr1 * a[3] + ki1 * a[2];
      int ch = p0 >> 2;
      Vl[ch * 264 + col * 4 + (p0 & 3)] = packpair(v0r, v0i);
      Vl[ch * 264 + col * 4 + ((p0 + 1) & 3)] = packpair(v1r, v1i);
    }
  }
  LGW();                              // our Vl ds_writes complete -> visible
  __builtin_amdgcn_s_barrier();       // raw barrier: does NOT drain the A prefetch

  // ---- phase 2: Y2(256 x 64) = Mc x [V2'; U2] ----
#pragma unroll
  for (int mt = 0; mt < 4; ++mt)
#pragma unroll
    for (int nt = 0; nt < 4; ++nt) acc[mt][nt] = (f4){0.f, 0.f, 0.f, 0.f};

#pragma unroll
  for (int i = 0; i < 6; ++i) {            // k in [0,192): B = V from LDS
    LGW();
    STAGE_A(Mch, Mcl, i + 1, (i + 1) & 1);
    VMW(8);                                // A(i) landed; A(i+1) in flight
    bf8v bh[4]; bFromV(i, bh); compute(i & 1, bh);
  }
  { // i = 6: start U prefetch for iters 8..15
    LGW(); STAGE_A(Mch, Mcl, 7, 1); LOAD_B(2, 0); VMW(24);
    bf8v bh[4]; bFromV(6, bh); compute(0, bh);
  }
  { // i = 7
    LGW(); STAGE_A(Mch, Mcl, 8, 0); LOAD_B(0, 1); VMW(40);
    bf8v bh[4]; bFromV(7, bh); compute(1, bh);
  }
#pragma unroll
  for (int i = 8; i < 14; ++i) {           // k in [256,448): B = U from registers
    LGW();
    STAGE_A(Mch, Mcl, i + 1, (i + 1) & 1);
    LOAD_B((i + 2) % 3, i + 2 - 8);
    VMW(40);
    bf8v bh[4]; bFromReg(i % 3, bh); compute(i & 1, bh);
  }
  { // i = 14
    LGW(); STAGE_A(Mch, Mcl, 15, 1); VMW(24);
    bf8v bh[4]; bFromReg(2, bh); compute(0, bh);
  }
  { // i = 15
    LGW(); VMW(0);
    bf8v bh[4]; bFromReg(0, bh); compute(1, bh);
  }

#pragma unroll
  for (int mt = 0; mt < 4; ++mt) {
    int r0 = w * 64 + mt * 16 + quad * 4;
    int h0 = r0 >> 1;   // even
#pragma unroll
    for (int nt = 0; nt < 4; ++nt) {
      int gcol = j0 + nt * 16 + ln;
      f4 a = acc[mt][nt];
      Yp[(size_t)h0 * NT + gcol] = make_float2(a[0], a[1]);
      Yp[(size_t)(h0 + 1) * NT + gcol] = make_float2(a[2], a[3]);
    }
  }
#undef STAGE_A
#undef LOAD_B
#undef VMW
#undef LGW
}

// ---------------- inverse rfft-4096 from float2 pair planes, fused exact GELU ----------------
__global__ __launch_bounds__(256) void fft_inv_gelu_pl(const float2* __restrict__ Yp,
                                                       float* __restrict__ out) {
  __shared__ cpx bufA[2112], bufB[2112];
  int t = threadIdx.x;
  int row = blockIdx.x;
  int b = row >> 7, h = row & 127;
  const float2* Yrow = Yp + (size_t)h * NT + (size_t)b * WB;
#pragma unroll
  for (int r = 0; r < 4; ++r) {
    int k = t + (r << 8);
    if (k == 0) {
      float y0 = Yrow[0].x;     // Im discarded (pocketfft irfft semantics)
      float yN = Yrow[2048].x;
      bufB[SW(0)] = make_float2(0.5f * (y0 + yN), 0.5f * (y0 - yN));
      float2 z = Yrow[1024];
      bufB[SW(1024)] = make_float2(z.x, -z.y);
    } else {
      float2 A = Yrow[k];
      float2 M = Yrow[2048 - k];
      float Br = M.x, Bi = -M.y;
      float sr = 0.5f * (A.x + Br), si = 0.5f * (A.y + Bi);
      float dr = 0.5f * (A.x - Br), di = 0.5f * (A.y - Bi);
      float th = (float)k * (PI_F / 2048.f);
      float sn, cs; __sincosf(th, &sn, &cs);
      float e1 = cs * di + sn * dr;
      float e2 = cs * dr - sn * di;
      bufB[SW(k)] = make_float2(sr - e1, si + e2);
      bufB[SW(2048 - k)] = make_float2(sr + e1, -si + e2);
    }
  }
  __syncthreads();
  cpx a[8];
#pragma unroll
  for (int j = 0; j < 8; ++j) a[j] = bufB[SW(t + 256 * j)];
  fft2048_core<1>(a, bufA, bufB, t);
  float2* dst = (float2*)(out + (size_t)row * NL);
  const float sc = 1.f / 2048.f;
#pragma unroll
  for (int r = 0; r < 8; ++r) {
    int n = t + (r << 8);
    cpx z = bufB[SW(n)];
    dst[n] = make_float2(gelu_exact(z.x * sc), gelu_exact(z.y * sc));
  }
}

// ================= FALLBACK (fp32 path, used only if ws too small) =================
__global__ __launch_bounds__(128) void fb_precomp(
    const float* __restrict__ C2, const float* __restrict__ B2,
    const float* __restrict__ D,
    float* __restrict__ Bt, float* __restrict__ Ct, float* __restrict__ Dt) {
  __shared__ float rc[128], rs[128];
  __shared__ float sTr[128], sTi[128];
  int x = blockIdx.x, t = threadIdx.x, which = blockIdx.y;
  { float s, c; sincosf(-(2.f * PI_F / 128.f) * (float)t, &s, &c); rc[t] = c; rs[t] = s; }
  __syncthreads();
  float sr = 0.f, si = 0.f;
  if (which == 0) {
    for (int k = 0; k < 128; ++k) {
      int j = (k * t) & 127; float c = rc[j], s = rs[j];
      float br = B2[(x * 128 + k) * 2], bi = B2[(x * 128 + k) * 2 + 1];
      sr += br * c - bi * s; si += br * s + bi * c;
    }
    Bt[(t * 128 + x) * 2] = sr; Bt[(t * 128 + x) * 2 + 1] = si;
  } else if (which == 1) {
    for (int k = 0; k < 128; ++k) {
      int j = (k * t) & 127; float c = rc[j], s = -rs[j];
      float cr = C2[(k * 128 + x) * 2], ci = C2[(k * 128 + x) * 2 + 1];
      sr += cr * c - ci * s; si += cr * s + ci * c;
    }
    Ct[(x * 128 + t) * 2] = sr * (1.f / 128.f);
    Ct[(x * 128 + t) * 2 + 1] = si * (1.f / 128.f);
  } else {
    for (int k = 0; k < 128; ++k) {
      int j = (k * x) & 127; float c = rc[j], s = rs[j];
      float d = D[t * 128 + k];
      sr += d * c; si += d * s;
    }
    sTr[t] = sr; sTi[t] = si;
    __syncthreads();
    sr = 0.f; si = 0.f;
    for (int k = 0; k < 128; ++k) {
      int j = (k * t) & 127; float c = rc[j], s = -rs[j];
      sr += sTr[k] * c - sTi[k] * s;
      si += sTr[k] * s + sTi[k] * c;
    }
    Dt[(x * 128 + t) * 2] = sr * (1.f / 128.f);
    Dt[(x * 128 + t) * 2 + 1] = si * (1.f / 128.f);
  }
}

__global__ __launch_bounds__(256) void fb_fft_fwd(const float* __restrict__ u,
                                                  cpx* __restrict__ U) {
  __shared__ cpx bufA[2112], bufB[2112];
  int t = threadIdx.x;
  int row = blockIdx.x;
  const cpx* src = (const cpx*)(u + (size_t)row * NL);
  cpx a[8];
#pragma unroll
  for (int j = 0; j < 8; ++j) a[j] = src[t + 256 * j];
  fft2048_core<-1>(a, bufA, bufB, t);
  cpx* Urow = U + (size_t)row * LF;
#pragma unroll
  for (int r = 0; r < 4; ++r) {
    int k = t + (r << 8);
    if (k == 0) {
      cpx z0 = bufB[SW(0)];
      Urow[0] = make_float2(z0.x + z0.y, 0.f);
      Urow[2048] = make_float2(z0.x - z0.y, 0.f);
      cpx zN = bufB[SW(1024)];
      Urow[1024] = make_float2(zN.x, -zN.y);
    } else {
      cpx A = bufB[SW(k)];
      cpx M = bufB[SW(2048 - k)];
      float Br = M.x, Bi = -M.y;
      float sr = 0.5f * (A.x + Br), si = 0.5f * (A.y + Bi);
      float dr = 0.5f * (A.x - Br), di = 0.5f * (A.y - Bi);
      float th = (float)k * (PI_F / 2048.f);
      float sn, cs; __sincosf(th, &sn, &cs);
      float tr = cs * dr + sn * di;
      float ti = cs * di - sn * dr;
      Urow[k] = make_float2(sr + ti, si - tr);
      float A2r = M.x, A2i = M.y;
      float B2r = A.x, B2i = -A.y;
      float s2r = 0.5f * (A2r + B2r), s2i = 0.5f * (A2i + B2i);
      float d2r = 0.5f * (A2r - B2r), d2i = 0.5f * (A2i - B2i);
      float t2r = -cs * d2r + sn * d2i;
      float t2i = -cs * d2i - sn * d2r;
      Urow[2048 - k] = make_float2(s2r + t2i, s2i - t2r);
    }
  }
}

__device__ __forceinline__ void ld4(float4 d[4], const float4* __restrict__ p) {
#pragma unroll
  for (int kk = 0; kk < 4; ++kk) d[kk] = p[kk];
}
__device__ __forceinline__ void cmac4(const float4 m[4], float xr, float xi,
                                      float ar[8], float ai[8]) {
#pragma unroll
  for (int kk = 0; kk < 4; ++kk) {
    float4 v = m[kk];
    ar[2 * kk]     = fmaf(v.x, xr, fmaf(-v.y, xi, ar[2 * kk]));
    ai[2 * kk]     = fmaf(v.x, xi, fmaf( v.y, xr, ai[2 * kk]));
    ar[2 * kk + 1] = fmaf(v.z, xr, fmaf(-v.w, xi, ar[2 * kk + 1]));
    ai[2 * kk + 1] = fmaf(v.z, xi, fmaf( v.w, xr, ai[2 * kk + 1]));
  }
}

__global__ __launch_bounds__(256) void fb_mix(
    const cpx* __restrict__ U,
    const float* __restrict__ Bt, const float* __restrict__ Ct,
    const float* __restrict__ Dt, const float* __restrict__ Lam,
    cpx* __restrict__ Y) {
  __shared__ cpx sU[128][17], sV[128][17];
  int tid = threadIdx.x;
  int b = blockIdx.y;
  size_t ub = (size_t)b * NH * LF;
  if (blockIdx.x == 128) {
    int t = tid;
    if (t < 128) sU[t][0] = U[ub + (size_t)t * LF + 2048];
    __syncthreads();
    if (t < 128) {
      float ar = 0.f, ai = 0.f;
      for (int q = 0; q < 128; ++q) {
        float ur = sU[q][0].x, ui = sU[q][0].y;
        float br = Bt[(q * 128 + t) * 2], bi = Bt[(q * 128 + t) * 2 + 1];
        ar = fmaf(br, ur, fmaf(-bi, ui, ar));
        ai = fmaf(br, ui, fmaf(bi, ur, ai));
      }
      float a = Lam[2 * t], bb = Lam[2 * t + 1];
      float dx = -a, dy = PI_F - bb;
      float inv = 1.f / (dx * dx + dy * dy);
      float kr = dx * inv, ki = -dy * inv;
      sV[t][0] = make_float2(kr * ar - ki * ai, kr * ai + ki * ar);
    }
    __syncthreads();
    if (t < 128) {
      float ar = 0.f, ai = 0.f;
      for (int q = 0; q < 128; ++q) {
        float ur = sU[q][0].x, ui = sU[q][0].y;
        float vr = sV[q][0].x, vi = sV[q][0].y;
        float cr = Ct[(q * 128 + t) * 2], ci = Ct[(q * 128 + t) * 2 + 1];
        float dr = Dt[(q * 128 + t) * 2], di = Dt[(q * 128 + t) * 2 + 1];
        ar += cr * vr - ci * vi + dr * ur - di * ui;
        ai += cr * vi + ci * vr + dr * ui + di * ur;
      }
      Y[ub + (size_t)t * LF + 2048] = make_float2(ar, ai);
    }
    return;
  }
  int lane = tid & 15, g = tid >> 4;
  int l = blockIdx.x * 16 + lane;
#pragma unroll
  for (int rep = 0; rep < 8; ++rep) {
    int q = rep * 16 + g;
    sU[q][lane] = U[ub + (size_t)q * LF + l];
  }
  __syncthreads();
  float omega = (float)l * (PI_F / 2048.f);
  float ar[8], ai[8];
  {
#pragma unroll
    for (int k = 0; k < 8; ++k) { ar[k] = 0.f; ai[k] = 0.f; }
    const float4* base = (const float4*)Bt + g * 4;
    float4 e[4], o[4];
    ld4(e, base);
#pragma unroll 1
    for (int q = 0; q < 128; q += 2) {
      ld4(o, base + (q + 1) * 64);
      cpx u0 = sU[q][lane];
      cmac4(e, u0.x, u0.y, ar, ai);
      ld4(e, base + ((q + 2) & 127) * 64);
      cpx u1 = sU[q + 1][lane];
      cmac4(o, u1.x, u1.y, ar, ai);
    }
    int p0 = g * 8;
#pragma unroll
    for (int k = 0; k < 8; ++k) {
      int p = p0 + k;
      float a = Lam[2 * p], bb = Lam[2 * p + 1];
      float dx = -a, dy = omega - bb;
      float inv = 1.f / (dx * dx + dy * dy);
      float kr = dx * inv, ki = -dy * inv;
      sV[p][lane] = make_float2(kr * ar[k] - ki * ai[k], kr * ai[k] + ki * ar[k]);
    }
  }
  __syncthreads();
  {
#pragma unroll
    for (int k = 0; k < 8; ++k) { ar[k] = 0.f; ai[k] = 0.f; }
    const float4* base = (const float4*)Ct + g * 4;
    float4 e[4], o[4];
    ld4(e, base);
#pragma unroll 1
    for (int q = 0; q < 128; q += 2) {
      ld4(o, base + (q + 1) * 64);
      cpx v0 = sV[q][lane];
      cmac4(e, v0.x, v0.y, ar, ai);
      ld4(e, base + ((q + 2) & 127) * 64);
      cpx v1 = sV[q + 1][lane];
      cmac4(o, v1.x, v1.y, ar, ai);
    }
  }
  {
    const float4* base = (const float4*)Dt + g * 4;
    float4 e[4], o[4];
    ld4(e, base);
#pragma unroll 1
    for (int q = 0; q < 128; q += 2) {
      ld4(o, base + (q + 1) * 64);
      cpx u0 = sU[q][lane];
      cmac4(e, u0.x, u0.y, ar, ai);
      ld4(e, base + ((q + 2) & 127) * 64);
      cpx u1 = sU[q + 1][lane];
      cmac4(o, u1.x, u1.y, ar, ai);
    }
  }
  int h0 = g * 8;
#pragma unroll
  for (int k = 0; k < 8; ++k) {
    Y[ub + (size_t)(h0 + k) * LF + l] = make_float2(ar[k], ai[k]);
  }
}

__global__ __launch_bounds__(256) void fb_fft_inv(const cpx* __restrict__ Y,
                                                  float* __restrict__ out) {
  __shared__ cpx bufA[2112], bufB[2112];
  int t = threadIdx.x;
  int row = blockIdx.x;
  const cpx* Yrow = Y + (size_t)row * LF;
#pragma unroll
  for (int r = 0; r < 4; ++r) {
    int k = t + (r << 8);
    if (k == 0) {
      float y0 = Yrow[0].x;
      float yN = Yrow[2048].x;
      bufB[SW(0)] = make_float2(0.5f * (y0 + yN), 0.5f * (y0 - yN));
      cpx z = Yrow[1024];
      bufB[SW(1024)] = make_float2(z.x, -z.y);
    } else {
      cpx A = Yrow[k];
      cpx M = Yrow[2048 - k];
      float Br = M.x, Bi = -M.y;
      float sr = 0.5f * (A.x + Br), si = 0.5f * (A.y + Bi);
      float dr = 0.5f * (A.x - Br), di = 0.5f * (A.y - Bi);
      float th = (float)k * (PI_F / 2048.f);
      float sn, cs; __sincosf(th, &sn, &cs);
      float e1 = cs * di + sn * dr;
      float e2 = cs * dr - sn * di;
      bufB[SW(k)] = make_float2(sr - e1, si + e2);
      bufB[SW(2048 - k)] = make_float2(sr + e1, -si + e2);
    }
  }
  __syncthreads();
  cpx a[8];
#pragma unroll
  for (int j = 0; j < 8; ++j) a[j] = bufB[SW(t + 256 * j)];
  fft2048_core<1>(a, bufA, bufB, t);
  float2* dst = (float2*)(out + (size_t)row * NL);
  const float sc = 1.f / 2048.f;
#pragma unroll
  for (int r = 0; r < 8; ++r) {
    int n = t + (r << 8);
    cpx z = bufB[SW(n)];
    dst[n] = make_float2(gelu_exact(z.x * sc), gelu_exact(z.y * sc));
  }
}

extern "C" void kernel_launch(void* const* d_in, const int* in_sizes, int n_in,
                              void* d_out, int out_size, void* d_ws, size_t ws_size,
                              hipStream_t stream) {
  const float* u   = (const float*)d_in[0];
  const float* C2  = (const float*)d_in[1];
  const float* B2  = (const float*)d_in[2];
  const float* D   = (const float*)d_in[3];
  const float* Lam = (const float*)d_in[4];
  float* out = (float*)d_out;

  const size_t PL = (size_t)128 * NT;                 // dwords per pair plane
  const size_t need = PL * 4                          // Uph
                    + PL * 8                          // Yp float2
                    + 2 * 65536 * 2 + 2 * 131072 * 2; // Mb, Mc bf16 hi/lo

  if (ws_size >= need) {
    unsigned int* Uph = (unsigned int*)d_ws;
    float2* Yp = (float2*)(Uph + PL);
    unsigned short* Mbh = (unsigned short*)(Yp + PL);
    unsigned short* Mbl = Mbh + 65536;
    unsigned short* Mch = Mbl + 65536;
    unsigned short* Mcl = Mch + 131072;

    fwd_pre<<<192 + NB * NH, 256, 0, stream>>>(u, C2, B2, D, Uph, Mbh, Mbl, Mch, Mcl);
    gemm_fused<<<NT / 64, 256, 0, stream>>>(Mbh, Mbl, Mch, Mcl, Uph, Lam, Yp);
    fft_inv_gelu_pl<<<NB * NH, 256, 0, stream>>>(Yp, out);
  } else {
    float* ws = (float*)d_ws;
    const size_t nUc = (size_t)NB * NH * LF;
    cpx* U  = (cpx*)ws;
    cpx* Yf = U;
    float* Bt = ws + 2 * nUc;
    float* Ct = Bt + 32768;
    float* Dt = Ct + 32768;
    fb_precomp<<<dim3(128, 3), 128, 0, stream>>>(C2, B2, D, Bt, Ct, Dt);
    fb_fft_fwd<<<NB * NH, 256, 0, stream>>>(u, U);
    fb_mix<<<dim3(129, NB), 256, 0, stream>>>(U, Bt, Ct, Dt, Lam, Yf);
    fb_fft_inv<<<NB * NH, 256, 0, stream>>>(Yf, out);
  }
}

// Round 3
// 125.082 us; speedup vs baseline: 1.1213x; 1.1213x over previous
//
#include <hip/hip_runtime.h>
#include <math.h>

#define PI_F 3.14159265358979323846f
#define NB 8
#define NH 128
#define NL 4096
#define LF 2049    // NL/2 + 1
#define WB 2064    // padded per-batch column width (>=2049, mult of 16)
#define NT 16512   // WB * NB = total GEMM columns

typedef float2 cpx;
typedef __attribute__((ext_vector_type(8))) short bf8v;   // 8 bf16 in 4 VGPRs
typedef __attribute__((ext_vector_type(4))) float f4;     // MFMA acc

#define MFMA16(a, b, c) __builtin_amdgcn_mfma_f32_16x16x32_bf16(a, b, c, 0, 0, 0)

__device__ __forceinline__ float gelu_exact(float x) {
  return 0.5f * x * (1.0f + erff(x * 0.70710678118654752f));
}
__device__ __forceinline__ unsigned short f2bf(float f) {
  unsigned int x = __float_as_uint(f);
  return (unsigned short)((x + 0x7FFFu + ((x >> 16) & 1u)) >> 16);
}
__device__ __forceinline__ float bf2f(unsigned short h) {
  return __uint_as_float((unsigned int)h << 16);
}
__device__ __forceinline__ unsigned int packpair(float re, float im) {
  return (unsigned int)f2bf(re) | ((unsigned int)f2bf(im) << 16);
}
__device__ __forceinline__ cpx cadd(cpx a, cpx b) { return make_float2(a.x + b.x, a.y + b.y); }
__device__ __forceinline__ cpx csub(cpx a, cpx b) { return make_float2(a.x - b.x, a.y - b.y); }
__device__ __forceinline__ cpx cmul(cpx a, cpx b) {
  return make_float2(fmaf(a.x, b.x, -a.y * b.y), fmaf(a.x, b.y, a.y * b.x));
}
template <int SGN>
__device__ __forceinline__ cpx mulJ(cpx a) {
  return (SGN < 0) ? make_float2(a.y, -a.x) : make_float2(-a.y, a.x);
}

// Pre-swizzled global layout for Mb/Mc: tile = k>>5 (256 rows x 32 k per tile,
// 8192 shorts), slot = m*4 + ((k>>3 & 3) ^ (m & 3)), elem = k&7.  Makes the
// GEMM A-staging a LINEAR copy (global_load_lds) with the XOR-swizzle baked
// into the source (both-sides-or-neither rule).
__device__ __forceinline__ void wrM(unsigned short* __restrict__ H,
                                    unsigned short* __restrict__ L,
                                    int m, int k, float v) {
  size_t a = (size_t)(k >> 5) * 8192 +
             (size_t)(m * 4 + (((k >> 3) & 3) ^ (m & 3))) * 8 + (k & 7);
  unsigned short h = f2bf(v);
  H[a] = h;
  L[a] = f2bf(v - bf2f(h));
}

// async global->LDS, 16B per lane; LDS dest is wave-uniform base + lane*16.
__device__ __forceinline__ void gload16(const unsigned short* g, unsigned short* l) {
  __builtin_amdgcn_global_load_lds(
      (const __attribute__((address_space(1))) unsigned int*)g,
      (__attribute__((address_space(3))) unsigned int*)l, 16, 0, 0);
}

// ---------------- register FFT-2048: radix 8*8*8*4, 256 threads ----------------
#define SW(k) ((k) ^ (((k) >> 4) & 31))

template <int SGN>
__device__ __forceinline__ void dft8(cpx a[8]) {
  cpx t0 = cadd(a[0], a[4]), u0 = csub(a[0], a[4]);
  cpx t1 = cadd(a[1], a[5]), u1 = csub(a[1], a[5]);
  cpx t2 = cadd(a[2], a[6]), u2 = csub(a[2], a[6]);
  cpx t3 = cadd(a[3], a[7]), u3 = csub(a[3], a[7]);
  cpx E0 = cadd(t0, t2), E2 = csub(t0, t2);
  cpx ju2 = mulJ<SGN>(u2);
  cpx E1 = cadd(u0, ju2), E3 = csub(u0, ju2);
  cpx O0 = cadd(t1, t3), O2 = csub(t1, t3);
  cpx ju3 = mulJ<SGN>(u3);
  cpx O1 = cadd(u1, ju3), O3 = csub(u1, ju3);
  const float r = 0.70710678118654752f;
  const float S = (float)SGN;
  cpx w1O1 = make_float2(r * (O1.x - S * O1.y), r * (O1.y + S * O1.x));
  cpx w3O3 = make_float2(r * (-O3.x - S * O3.y), r * (S * O3.x - O3.y));
  cpx jO2 = mulJ<SGN>(O2);
  a[0] = cadd(E0, O0);   a[4] = csub(E0, O0);
  a[1] = cadd(E1, w1O1); a[5] = csub(E1, w1O1);
  a[2] = cadd(E2, jO2);  a[6] = csub(E2, jO2);
  a[3] = cadd(E3, w3O3); a[7] = csub(E3, w3O3);
}

template <int SGN>
__device__ __forceinline__ void dft4(cpx b[4]) {
  cpx s0 = cadd(b[0], b[2]), d0 = csub(b[0], b[2]);
  cpx s1 = cadd(b[1], b[3]), d1 = csub(b[1], b[3]);
  cpx jd1 = mulJ<SGN>(d1);
  b[0] = cadd(s0, s1); b[2] = csub(s0, s1);
  b[1] = cadd(d0, jd1); b[3] = csub(d0, jd1);
}

__device__ __forceinline__ void twid8(cpx a[8], float ang) {
  float s, c; __sincosf(ang, &s, &c);
  cpx w1 = make_float2(c, s);
  cpx w2 = cmul(w1, w1), w3 = cmul(w2, w1), w4 = cmul(w2, w2);
  cpx w5 = cmul(w3, w2), w6 = cmul(w3, w3), w7 = cmul(w4, w3);
  a[1] = cmul(a[1], w1); a[2] = cmul(a[2], w2); a[3] = cmul(a[3], w3);
  a[4] = cmul(a[4], w4); a[5] = cmul(a[5], w5); a[6] = cmul(a[6], w6);
  a[7] = cmul(a[7], w7);
}

template <int SGN>
__device__ __forceinline__ void fft2048_core(cpx a[8], cpx* __restrict__ bufA,
                                             cpx* __restrict__ bufB, int t) {
  const float S = (float)SGN;
  dft8<SGN>(a);
  twid8(a, S * (2.f * PI_F / 2048.f) * (float)t);
#pragma unroll
  for (int p = 0; p < 8; ++p) bufA[p * 264 + t] = a[p];
  __syncthreads();
  int p = t >> 5, n1 = t & 31;
#pragma unroll
  for (int j = 0; j < 8; ++j) a[j] = bufA[p * 264 + n1 + 32 * j];
  dft8<SGN>(a);
  twid8(a, S * (2.f * PI_F / 256.f) * (float)n1);
#pragma unroll
  for (int q = 0; q < 8; ++q) bufB[p * 264 + q * 33 + n1] = a[q];
  __syncthreads();
  int q = (t >> 2) & 7, n2 = t & 3;
#pragma unroll
  for (int j = 0; j < 8; ++j) a[j] = bufB[p * 264 + q * 33 + n2 + 4 * j];
  dft8<SGN>(a);
  twid8(a, S * (2.f * PI_F / 32.f) * (float)n2);
#pragma unroll
  for (int d = 0; d < 8; ++d) bufA[p * 264 + q * 33 + 4 * d + n2] = a[d];
  __syncthreads();
#pragma unroll
  for (int h = 0; h < 2; ++h) {
    int d = 2 * n2 + h;
    cpx b[4];
#pragma unroll
    for (int m = 0; m < 4; ++m) b[m] = bufA[p * 264 + q * 33 + 4 * d + m];
    dft4<SGN>(b);
    int kb = p + 8 * q + 64 * d;
#pragma unroll
    for (int c = 0; c < 4; ++c) bufB[SW(kb + 512 * c)] = b[c];
  }
  __syncthreads();
}

// ---------------- fused: precomp (blocks 0..191) + forward rfft-4096 pack ----------------
__global__ __launch_bounds__(256) void fwd_pre(
    const float* __restrict__ u,
    const float* __restrict__ C2, const float* __restrict__ B2,
    const float* __restrict__ D,
    unsigned int* __restrict__ Uph,
    unsigned short* __restrict__ Mbh, unsigned short* __restrict__ Mbl,
    unsigned short* __restrict__ Mch, unsigned short* __restrict__ Mcl) {
  __shared__ cpx bufA[2112], bufB[2112];
  int t = threadIdx.x;
  if (blockIdx.x < 192) {
    __shared__ float rc[128], rs[128];
    __shared__ float sOr[2][128], sOi[2][128];
    __shared__ float sTr[2][128], sTi[2][128];
    int e = blockIdx.x;
    int which = e >> 6;                 // 0: Mb, 1: C~, 2: D~ (uniform per block)
    int half = t >> 7, tt = t & 127;
    int x = (2 * e + half) & 127;
    { float s, c; sincosf(-(2.f * PI_F / 128.f) * (float)tt, &s, &c); rc[tt] = c; rs[tt] = s; }
    if (which == 0) {   // stage B~ source row x: B2[x*128 + k]
      float2 v = ((const float2*)B2)[(size_t)x * 128 + tt];
      sOr[half][tt] = v.x; sOi[half][tt] = v.y;
    } else if (which == 1) {  // stage C~ source column x: C2[k*128 + x]
      float2 v = ((const float2*)C2)[(size_t)tt * 128 + x];
      sOr[half][tt] = v.x; sOi[half][tt] = v.y;
    }
    __syncthreads();
    float sr = 0.f, si = 0.f;
    if (which == 0) {
#pragma unroll 4
      for (int k = 0; k < 128; ++k) {
        int j = (k * tt) & 127; float c = rc[j], s = rs[j];
        float br = sOr[half][k], bi = sOi[half][k];
        sr += br * c - bi * s; si += br * s + bi * c;
      }
      wrM(Mbh, Mbl, 2 * x,     2 * tt,     sr);
      wrM(Mbh, Mbl, 2 * x,     2 * tt + 1, -si);
      wrM(Mbh, Mbl, 2 * x + 1, 2 * tt,     si);
      wrM(Mbh, Mbl, 2 * x + 1, 2 * tt + 1,  sr);
    } else if (which == 1) {
#pragma unroll 4
      for (int k = 0; k < 128; ++k) {
        int j = (k * tt) & 127; float c = rc[j], s = -rs[j];  // e^{+i theta}
        float cr = sOr[half][k], ci = sOi[half][k];
        sr += cr * c - ci * s; si += cr * s + ci * c;
      }
      sr *= (1.f / 128.f); si *= (1.f / 128.f);
      wrM(Mch, Mcl, 2 * tt,     2 * x,     sr);
      wrM(Mch, Mcl, 2 * tt,     2 * x + 1, -si);
      wrM(Mch, Mcl, 2 * tt + 1, 2 * x,     si);
      wrM(Mch, Mcl, 2 * tt + 1, 2 * x + 1,  sr);
    } else {
#pragma unroll 8
      for (int k = 0; k < 128; ++k) {
        int j = (k * x) & 127; float c = rc[j], s = rs[j];
        float d = D[tt * 128 + k];
        sr += d * c; si += d * s;
      }
      sTr[half][tt] = sr; sTi[half][tt] = si;
      __syncthreads();
      sr = 0.f; si = 0.f;
#pragma unroll 4
      for (int k = 0; k < 128; ++k) {
        int j = (k * tt) & 127; float c = rc[j], s = -rs[j];
        sr += sTr[half][k] * c - sTi[half][k] * s;
        si += sTr[half][k] * s + sTi[half][k] * c;
      }
      sr *= (1.f / 128.f); si *= (1.f / 128.f);
      wrM(Mch, Mcl, 2 * tt,     256 + 2 * x,     sr);
      wrM(Mch, Mcl, 2 * tt,     256 + 2 * x + 1, -si);
      wrM(Mch, Mcl, 2 * tt + 1, 256 + 2 * x,     si);
      wrM(Mch, Mcl, 2 * tt + 1, 256 + 2 * x + 1,  sr);
    }
    return;
  }
  int row = blockIdx.x - 192;
  int b = row >> 7, q = row & 127;
  const cpx* src = (const cpx*)(u + (size_t)row * NL);
  cpx a[8];
#pragma unroll
  for (int j = 0; j < 8; ++j) a[j] = src[t + 256 * j];
  fft2048_core<-1>(a, bufA, bufB, t);
  unsigned int* Uh = Uph + (size_t)q * NT + (size_t)b * WB;
  auto pstore = [&](int k, float ur, float ui) { Uh[k] = packpair(ur, ui); };
#pragma unroll
  for (int r = 0; r < 4; ++r) {
    int k = t + (r << 8);
    if (k == 0) {
      cpx z0 = bufB[SW(0)];
      pstore(0, z0.x + z0.y, 0.f);
      pstore(2048, z0.x - z0.y, 0.f);
      cpx zN = bufB[SW(1024)];
      pstore(1024, zN.x, -zN.y);
    } else {
      cpx A = bufB[SW(k)];
      cpx M = bufB[SW(2048 - k)];
      float Br = M.x, Bi = -M.y;
      float sr = 0.5f * (A.x + Br), si = 0.5f * (A.y + Bi);
      float dr = 0.5f * (A.x - Br), di = 0.5f * (A.y - Bi);
      float th = (float)k * (PI_F / 2048.f);
      float sn, cs; __sincosf(th, &sn, &cs);
      float tr = cs * dr + sn * di;
      float ti = cs * di - sn * dr;
      pstore(k, sr + ti, si - tr);
      float A2r = M.x, A2i = M.y;
      float B2r = A.x, B2i = -A.y;
      float s2r = 0.5f * (A2r + B2r), s2i = 0.5f * (A2i + B2i);
      float d2r = 0.5f * (A2r - B2r), d2i = 0.5f * (A2i - B2i);
      float t2r = -cs * d2r + sn * d2i;
      float t2i = -cs * d2i - sn * d2r;
      pstore(2048 - k, s2r + t2i, s2i - t2r);
    }
  }
}

// ---------------- fused GEMM: V = k.(Mb U), Y = Mc [V; U] ----------------
// Balanced 256-block grid: 248 blocks x 64 cols + 8 blocks x 80 cols = 16512.
// Every CU gets exactly ONE block (no serial-tail quantization).  Templated
// body over NTT (= N-tiles of 16 cols).  A: per-wave global_load_lds from
// pre-swizzled Mb/Mc, double-buffered; B: depth-3 register ring; counted
// vmcnt, never 0 mid-loop; single raw s_barrier for the V handoff.
#define VSTR 324   // Vl chunk stride in dwords (80 cols * 4 + pad)

#define VMW(n) asm volatile("s_waitcnt vmcnt(" #n ")" ::: "memory")
#define LGW()  asm volatile("s_waitcnt lgkmcnt(0)" ::: "memory")

template <int NTT>
__device__ __forceinline__ void gemm_body(
    int j0, int tid,
    unsigned short (*Ah)[8192], unsigned short (*Al)[8192], unsigned int* Vl,
    const unsigned short* __restrict__ Mbh, const unsigned short* __restrict__ Mbl,
    const unsigned short* __restrict__ Mch, const unsigned short* __restrict__ Mcl,
    const unsigned int* __restrict__ Uph,
    const float* __restrict__ Lam,
    float2* __restrict__ Yp) {
  int w = tid >> 6, lane = tid & 63, quad = lane >> 4, ln = lane & 15;

  unsigned int breg[3][NTT][4];
  f4 acc[4][NTT];

#define STAGE_A(H, L, tile, buf)                                              \
  {                                                                           \
    size_t tb_ = (size_t)(tile) * 8192;                                       \
    _Pragma("unroll") for (int r_ = 0; r_ < 4; ++r_) {                        \
      int sb_ = w * 256 + r_ * 64;                                            \
      gload16((H) + tb_ + (size_t)(sb_ + lane) * 8, &Ah[buf][sb_ * 8]);       \
      gload16((L) + tb_ + (size_t)(sb_ + lane) * 8, &Al[buf][sb_ * 8]);       \
    }                                                                         \
  }
#define LOAD_B(g, it)                                                         \
  {                                                                           \
    _Pragma("unroll") for (int nt_ = 0; nt_ < NTT; ++nt_)                     \
      _Pragma("unroll") for (int c_ = 0; c_ < 4; ++c_)                        \
        breg[g][nt_][c_] =                                                    \
            Uph[(size_t)((it) * 16 + quad * 4 + c_) * NT + j0 + nt_ * 16 + ln]; \
  }
  // vmcnt ledger: A tile = 8 gloads, B tile = 4*NTT loads per wave.
#define VMW_STEADY() { if constexpr (NTT == 4) VMW(40); else VMW(48); }
#define VMW_T1()     { if constexpr (NTT == 4) VMW(24); else VMW(28); }

  auto bFromReg = [&](int g, bf8v bh[NTT]) {
#pragma unroll
    for (int nt = 0; nt < NTT; ++nt) {
      union { unsigned int u[4]; bf8v v; } cv;
#pragma unroll
      for (int c = 0; c < 4; ++c) cv.u[c] = breg[g][nt][c];
      bh[nt] = cv.v;
    }
  };
  auto bFromV = [&](int i, bf8v bh[NTT]) {
    const unsigned short* Vs = (const unsigned short*)Vl;
#pragma unroll
    for (int nt = 0; nt < NTT; ++nt)
      bh[nt] = *(const bf8v*)&Vs[(size_t)(i * 4 + quad) * (VSTR * 2) + (nt * 16 + ln) * 8];
  };
  auto compute = [&](int buf, const bf8v* bh) {
    bf8v ah[4], al[4];
#pragma unroll
    for (int mt = 0; mt < 4; ++mt) {
      int m = w * 64 + mt * 16 + ln;
      int off = (m * 4 + (quad ^ (m & 3))) * 8;
      ah[mt] = *(const bf8v*)&Ah[buf][off];
      al[mt] = *(const bf8v*)&Al[buf][off];
    }
#pragma unroll
    for (int mt = 0; mt < 4; ++mt)
#pragma unroll
      for (int nt = 0; nt < NTT; ++nt) {
        acc[mt][nt] = MFMA16(ah[mt], bh[nt], acc[mt][nt]);
        acc[mt][nt] = MFMA16(al[mt], bh[nt], acc[mt][nt]);
      }
  };

  // ---- phase 1: V(256 x 16*NTT) = Mb x U ----
  STAGE_A(Mbh, Mbl, 0, 0);
  LOAD_B(0, 0);
  LOAD_B(1, 1);
#pragma unroll
  for (int mt = 0; mt < 4; ++mt)
#pragma unroll
    for (int nt = 0; nt < NTT; ++nt) acc[mt][nt] = (f4){0.f, 0.f, 0.f, 0.f};

#pragma unroll
  for (int i = 0; i < 6; ++i) {
    LGW();
    STAGE_A(Mbh, Mbl, i + 1, (i + 1) & 1);
    LOAD_B((i + 2) % 3, i + 2);
    VMW_STEADY();
    bf8v bh[NTT]; bFromReg(i % 3, bh); compute(i & 1, bh);
  }
  { // i = 6
    LGW(); STAGE_A(Mbh, Mbl, 7, 1); VMW_T1();
    bf8v bh[NTT]; bFromReg(0, bh); compute(0, bh);
  }
  { // i = 7: also prefetch phase-2 A tile 0 into slot 0
    LGW(); STAGE_A(Mch, Mcl, 0, 0); VMW(8);
    bf8v bh[NTT]; bFromReg(1, bh); compute(1, bh);
  }

  // phase-1 epilogue: Cauchy scale, V -> LDS
#pragma unroll
  for (int mt = 0; mt < 4; ++mt) {
    int r0 = w * 64 + mt * 16 + quad * 4;
    int p0 = r0 >> 1;   // even
    float2 lam0 = ((const float2*)Lam)[p0];
    float2 lam1 = ((const float2*)Lam)[p0 + 1];
#pragma unroll
    for (int nt = 0; nt < NTT; ++nt) {
      int col = nt * 16 + ln;
      int gcol = j0 + col;
      int bb = gcol / WB; int l = gcol - bb * WB;
      float omega = (float)l * (PI_F / 2048.f);
      f4 a = acc[mt][nt];
      float dx0 = -lam0.x, dy0 = omega - lam0.y;
      float inv0 = 1.f / (dx0 * dx0 + dy0 * dy0);
      float kr0 = dx0 * inv0, ki0 = -dy0 * inv0;
      float v0r = kr0 * a[0] - ki0 * a[1];
      float v0i = kr0 * a[1] + ki0 * a[0];
      float dx1 = -lam1.x, dy1 = omega - lam1.y;
      float inv1 = 1.f / (dx1 * dx1 + dy1 * dy1);
      float kr1 = dx1 * inv1, ki1 = -dy1 * inv1;
      float v1r = kr1 * a[2] - ki1 * a[3];
      float v1i = kr1 * a[3] + ki1 * a[2];
      int ch = p0 >> 2;
      Vl[ch * VSTR + col * 4 + (p0 & 3)] = packpair(v0r, v0i);
      Vl[ch * VSTR + col * 4 + ((p0 + 1) & 3)] = packpair(v1r, v1i);
    }
  }
  LGW();                              // Vl ds_writes complete -> visible
  __builtin_amdgcn_s_barrier();       // raw barrier: does NOT drain the A prefetch

  // ---- phase 2: Y(256 x 16*NTT) = Mc x [V; U] ----
#pragma unroll
  for (int mt = 0; mt < 4; ++mt)
#pragma unroll
    for (int nt = 0; nt < NTT; ++nt) acc[mt][nt] = (f4){0.f, 0.f, 0.f, 0.f};

#pragma unroll
  for (int i = 0; i < 6; ++i) {            // k in [0,192): B = V from LDS
    LGW();
    STAGE_A(Mch, Mcl, i + 1, (i + 1) & 1);
    VMW(8);
    bf8v bh[NTT]; bFromV(i, bh); compute(i & 1, bh);
  }
  { // i = 6: start U prefetch for iters 8..15
    LGW(); STAGE_A(Mch, Mcl, 7, 1); LOAD_B(2, 0); VMW_T1();
    bf8v bh[NTT]; bFromV(6, bh); compute(0, bh);
  }
  { // i = 7
    LGW(); STAGE_A(Mch, Mcl, 8, 0); LOAD_B(0, 1); VMW_STEADY();
    bf8v bh[NTT]; bFromV(7, bh); compute(1, bh);
  }
#pragma unroll
  for (int i = 8; i < 14; ++i) {           // k in [256,448): B = U from registers
    LGW();
    STAGE_A(Mch, Mcl, i + 1, (i + 1) & 1);
    LOAD_B((i + 2) % 3, i + 2 - 8);
    VMW_STEADY();
    bf8v bh[NTT]; bFromReg(i % 3, bh); compute(i & 1, bh);
  }
  { // i = 14
    LGW(); STAGE_A(Mch, Mcl, 15, 1); VMW_T1();
    bf8v bh[NTT]; bFromReg(2, bh); compute(0, bh);
  }
  { // i = 15
    LGW(); VMW(0);
    bf8v bh[NTT]; bFromReg(0, bh); compute(1, bh);
  }

#pragma unroll
  for (int mt = 0; mt < 4; ++mt) {
    int r0 = w * 64 + mt * 16 + quad * 4;
    int h0 = r0 >> 1;   // even
#pragma unroll
    for (int nt = 0; nt < NTT; ++nt) {
      int gcol = j0 + nt * 16 + ln;
      f4 a = acc[mt][nt];
      Yp[(size_t)h0 * NT + gcol] = make_float2(a[0], a[1]);
      Yp[(size_t)(h0 + 1) * NT + gcol] = make_float2(a[2], a[3]);
    }
  }
#undef STAGE_A
#undef LOAD_B
#undef VMW_STEADY
#undef VMW_T1
}

__global__ __launch_bounds__(256, 1) void gemm_fused(
    const unsigned short* __restrict__ Mbh, const unsigned short* __restrict__ Mbl,
    const unsigned short* __restrict__ Mch, const unsigned short* __restrict__ Mcl,
    const unsigned int* __restrict__ Uph,
    const float* __restrict__ Lam,
    float2* __restrict__ Yp) {
  __shared__ unsigned short Ah[2][8192], Al[2][8192];  // 64 KB, slot-swizzled
  __shared__ unsigned int Vl[32 * VSTR];               // 41.5 KB
  int tid = threadIdx.x;
  int bid = blockIdx.x;
  if (bid < 248) {
    gemm_body<4>(bid * 64, tid, Ah, Al, Vl, Mbh, Mbl, Mch, Mcl, Uph, Lam, Yp);
  } else {
    gemm_body<5>(248 * 64 + (bid - 248) * 80, tid, Ah, Al, Vl, Mbh, Mbl, Mch, Mcl, Uph, Lam, Yp);
  }
}

// ---------------- inverse rfft-4096 from float2 pair planes, fused exact GELU ----------------
__global__ __launch_bounds__(256) void fft_inv_gelu_pl(const float2* __restrict__ Yp,
                                                       float* __restrict__ out) {
  __shared__ cpx bufA[2112], bufB[2112];
  int t = threadIdx.x;
  int row = blockIdx.x;
  int b = row >> 7, h = row & 127;
  const float2* Yrow = Yp + (size_t)h * NT + (size_t)b * WB;
#pragma unroll
  for (int r = 0; r < 4; ++r) {
    int k = t + (r << 8);
    if (k == 0) {
      float y0 = Yrow[0].x;     // Im discarded (pocketfft irfft semantics)
      float yN = Yrow[2048].x;
      bufB[SW(0)] = make_float2(0.5f * (y0 + yN), 0.5f * (y0 - yN));
      float2 z = Yrow[1024];
      bufB[SW(1024)] = make_float2(z.x, -z.y);
    } else {
      float2 A = Yrow[k];
      float2 M = Yrow[2048 - k];
      float Br = M.x, Bi = -M.y;
      float sr = 0.5f * (A.x + Br), si = 0.5f * (A.y + Bi);
      float dr = 0.5f * (A.x - Br), di = 0.5f * (A.y - Bi);
      float th = (float)k * (PI_F / 2048.f);
      float sn, cs; __sincosf(th, &sn, &cs);
      float e1 = cs * di + sn * dr;
      float e2 = cs * dr - sn * di;
      bufB[SW(k)] = make_float2(sr - e1, si + e2);
      bufB[SW(2048 - k)] = make_float2(sr + e1, -si + e2);
    }
  }
  __syncthreads();
  cpx a[8];
#pragma unroll
  for (int j = 0; j < 8; ++j) a[j] = bufB[SW(t + 256 * j)];
  fft2048_core<1>(a, bufA, bufB, t);
  float2* dst = (float2*)(out + (size_t)row * NL);
  const float sc = 1.f / 2048.f;
#pragma unroll
  for (int r = 0; r < 8; ++r) {
    int n = t + (r << 8);
    cpx z = bufB[SW(n)];
    dst[n] = make_float2(gelu_exact(z.x * sc), gelu_exact(z.y * sc));
  }
}

// ================= FALLBACK (fp32 path, used only if ws too small) =================
__global__ __launch_bounds__(128) void fb_precomp(
    const float* __restrict__ C2, const float* __restrict__ B2,
    const float* __restrict__ D,
    float* __restrict__ Bt, float* __restrict__ Ct, float* __restrict__ Dt) {
  __shared__ float rc[128], rs[128];
  __shared__ float sTr[128], sTi[128];
  int x = blockIdx.x, t = threadIdx.x, which = blockIdx.y;
  { float s, c; sincosf(-(2.f * PI_F / 128.f) * (float)t, &s, &c); rc[t] = c; rs[t] = s; }
  __syncthreads();
  float sr = 0.f, si = 0.f;
  if (which == 0) {
    for (int k = 0; k < 128; ++k) {
      int j = (k * t) & 127; float c = rc[j], s = rs[j];
      float br = B2[(x * 128 + k) * 2], bi = B2[(x * 128 + k) * 2 + 1];
      sr += br * c - bi * s; si += br * s + bi * c;
    }
    Bt[(t * 128 + x) * 2] = sr; Bt[(t * 128 + x) * 2 + 1] = si;
  } else if (which == 1) {
    for (int k = 0; k < 128; ++k) {
      int j = (k * t) & 127; float c = rc[j], s = -rs[j];
      float cr = C2[(k * 128 + x) * 2], ci = C2[(k * 128 + x) * 2 + 1];
      sr += cr * c - ci * s; si += cr * s + ci * c;
    }
    Ct[(x * 128 + t) * 2] = sr * (1.f / 128.f);
    Ct[(x * 128 + t) * 2 + 1] = si * (1.f / 128.f);
  } else {
    for (int k = 0; k < 128; ++k) {
      int j = (k * x) & 127; float c = rc[j], s = rs[j];
      float d = D[t * 128 + k];
      sr += d * c; si += d * s;
    }
    sTr[t] = sr; sTi[t] = si;
    __syncthreads();
    sr = 0.f; si = 0.f;
    for (int k = 0; k < 128; ++k) {
      int j = (k * t) & 127; float c = rc[j], s = -rs[j];
      sr += sTr[k] * c - sTi[k] * s;
      si += sTr[k] * s + sTi[k] * c;
    }
    Dt[(x * 128 + t) * 2] = sr * (1.f / 128.f);
    Dt[(x * 128 + t) * 2 + 1] = si * (1.f / 128.f);
  }
}

__global__ __launch_bounds__(256) void fb_fft_fwd(const float* __restrict__ u,
                                                  cpx* __restrict__ U) {
  __shared__ cpx bufA[2112], bufB[2112];
  int t = threadIdx.x;
  int row = blockIdx.x;
  const cpx* src = (const cpx*)(u + (size_t)row * NL);
  cpx a[8];
#pragma unroll
  for (int j = 0; j < 8; ++j) a[j] = src[t + 256 * j];
  fft2048_core<-1>(a, bufA, bufB, t);
  cpx* Urow = U + (size_t)row * LF;
#pragma unroll
  for (int r = 0; r < 4; ++r) {
    int k = t + (r << 8);
    if (k == 0) {
      cpx z0 = bufB[SW(0)];
      Urow[0] = make_float2(z0.x + z0.y, 0.f);
      Urow[2048] = make_float2(z0.x - z0.y, 0.f);
      cpx zN = bufB[SW(1024)];
      Urow[1024] = make_float2(zN.x, -zN.y);
    } else {
      cpx A = bufB[SW(k)];
      cpx M = bufB[SW(2048 - k)];
      float Br = M.x, Bi = -M.y;
      float sr = 0.5f * (A.x + Br), si = 0.5f * (A.y + Bi);
      float dr = 0.5f * (A.x - Br), di = 0.5f * (A.y - Bi);
      float th = (float)k * (PI_F / 2048.f);
      float sn, cs; __sincosf(th, &sn, &cs);
      float tr = cs * dr + sn * di;
      float ti = cs * di - sn * dr;
      Urow[k] = make_float2(sr + ti, si - tr);
      float A2r = M.x, A2i = M.y;
      float B2r = A.x, B2i = -A.y;
      float s2r = 0.5f * (A2r + B2r), s2i = 0.5f * (A2i + B2i);
      float d2r = 0.5f * (A2r - B2r), d2i = 0.5f * (A2i - B2i);
      float t2r = -cs * d2r + sn * d2i;
      float t2i = -cs * d2i - sn * d2r;
      Urow[2048 - k] = make_float2(s2r + t2i, s2i - t2r);
    }
  }
}

__device__ __forceinline__ void ld4(float4 d[4], const float4* __restrict__ p) {
#pragma unroll
  for (int kk = 0; kk < 4; ++kk) d[kk] = p[kk];
}
__device__ __forceinline__ void cmac4(const float4 m[4], float xr, float xi,
                                      float ar[8], float ai[8]) {
#pragma unroll
  for (int kk = 0; kk < 4; ++kk) {
    float4 v = m[kk];
    ar[2 * kk]     = fmaf(v.x, xr, fmaf(-v.y, xi, ar[2 * kk]));
    ai[2 * kk]     = fmaf(v.x, xi, fmaf( v.y, xr, ai[2 * kk]));
    ar[2 * kk + 1] = fmaf(v.z, xr, fmaf(-v.w, xi, ar[2 * kk + 1]));
    ai[2 * kk + 1] = fmaf(v.z, xi, fmaf( v.w, xr, ai[2 * kk + 1]));
  }
}

__global__ __launch_bounds__(256) void fb_mix(
    const cpx* __restrict__ U,
    const float* __restrict__ Bt, const float* __restrict__ Ct,
    const float* __restrict__ Dt, const float* __restrict__ Lam,
    cpx* __restrict__ Y) {
  __shared__ cpx sU[128][17], sV[128][17];
  int tid = threadIdx.x;
  int b = blockIdx.y;
  size_t ub = (size_t)b * NH * LF;
  if (blockIdx.x == 128) {
    int t = tid;
    if (t < 128) sU[t][0] = U[ub + (size_t)t * LF + 2048];
    __syncthreads();
    if (t < 128) {
      float ar = 0.f, ai = 0.f;
      for (int q = 0; q < 128; ++q) {
        float ur = sU[q][0].x, ui = sU[q][0].y;
        float br = Bt[(q * 128 + t) * 2], bi = Bt[(q * 128 + t) * 2 + 1];
        ar = fmaf(br, ur, fmaf(-bi, ui, ar));
        ai = fmaf(br, ui, fmaf(bi, ur, ai));
      }
      float a = Lam[2 * t], bb = Lam[2 * t + 1];
      float dx = -a, dy = PI_F - bb;
      float inv = 1.f / (dx * dx + dy * dy);
      float kr = dx * inv, ki = -dy * inv;
      sV[t][0] = make_float2(kr * ar - ki * ai, kr * ai + ki * ar);
    }
    __syncthreads();
    if (t < 128) {
      float ar = 0.f, ai = 0.f;
      for (int q = 0; q < 128; ++q) {
        float ur = sU[q][0].x, ui = sU[q][0].y;
        float vr = sV[q][0].x, vi = sV[q][0].y;
        float cr = Ct[(q * 128 + t) * 2], ci = Ct[(q * 128 + t) * 2 + 1];
        float dr = Dt[(q * 128 + t) * 2], di = Dt[(q * 128 + t) * 2 + 1];
        ar += cr * vr - ci * vi + dr * ur - di * ui;
        ai += cr * vi + ci * vr + dr * ui + di * ur;
      }
      Y[ub + (size_t)t * LF + 2048] = make_float2(ar, ai);
    }
    return;
  }
  int lane = tid & 15, g = tid >> 4;
  int l = blockIdx.x * 16 + lane;
#pragma unroll
  for (int rep = 0; rep < 8; ++rep) {
    int q = rep * 16 + g;
    sU[q][lane] = U[ub + (size_t)q * LF + l];
  }
  __syncthreads();
  float omega = (float)l * (PI_F / 2048.f);
  float ar[8], ai[8];
  {
#pragma unroll
    for (int k = 0; k < 8; ++k) { ar[k] = 0.f; ai[k] = 0.f; }
    const float4* base = (const float4*)Bt + g * 4;
    float4 e[4], o[4];
    ld4(e, base);
#pragma unroll 1
    for (int q = 0; q < 128; q += 2) {
      ld4(o, base + (q + 1) * 64);
      cpx u0 = sU[q][lane];
      cmac4(e, u0.x, u0.y, ar, ai);
      ld4(e, base + ((q + 2) & 127) * 64);
      cpx u1 = sU[q + 1][lane];
      cmac4(o, u1.x, u1.y, ar, ai);
    }
    int p0 = g * 8;
#pragma unroll
    for (int k = 0; k < 8; ++k) {
      int p = p0 + k;
      float a = Lam[2 * p], bb = Lam[2 * p + 1];
      float dx = -a, dy = omega - bb;
      float inv = 1.f / (dx * dx + dy * dy);
      float kr = dx * inv, ki = -dy * inv;
      sV[p][lane] = make_float2(kr * ar[k] - ki * ai[k], kr * ai[k] + ki * ar[k]);
    }
  }
  __syncthreads();
  {
#pragma unroll
    for (int k = 0; k < 8; ++k) { ar[k] = 0.f; ai[k] = 0.f; }
    const float4* base = (const float4*)Ct + g * 4;
    float4 e[4], o[4];
    ld4(e, base);
#pragma unroll 1
    for (int q = 0; q < 128; q += 2) {
      ld4(o, base + (q + 1) * 64);
      cpx v0 = sV[q][lane];
      cmac4(e, v0.x, v0.y, ar, ai);
      ld4(e, base + ((q + 2) & 127) * 64);
      cpx v1 = sV[q + 1][lane];
      cmac4(o, v1.x, v1.y, ar, ai);
    }
  }
  {
    const float4* base = (const float4*)Dt + g * 4;
    float4 e[4], o[4];
    ld4(e, base);
#pragma unroll 1
    for (int q = 0; q < 128; q += 2) {
      ld4(o, base + (q + 1) * 64);
      cpx u0 = sU[q][lane];
      cmac4(e, u0.x, u0.y, ar, ai);
      ld4(e, base + ((q + 2) & 127) * 64);
      cpx u1 = sU[q + 1][lane];
      cmac4(o, u1.x, u1.y, ar, ai);
    }
  }
  int h0 = g * 8;
#pragma unroll
  for (int k = 0; k < 8; ++k) {
    Y[ub + (size_t)(h0 + k) * LF + l] = make_float2(ar[k], ai[k]);
  }
}

__global__ __launch_bounds__(256) void fb_fft_inv(const cpx* __restrict__ Y,
                                                  float* __restrict__ out) {
  __shared__ cpx bufA[2112], bufB[2112];
  int t = threadIdx.x;
  int row = blockIdx.x;
  const cpx* Yrow = Y + (size_t)row * LF;
#pragma unroll
  for (int r = 0; r < 4; ++r) {
    int k = t + (r << 8);
    if (k == 0) {
      float y0 = Yrow[0].x;
      float yN = Yrow[2048].x;
      bufB[SW(0)] = make_float2(0.5f * (y0 + yN), 0.5f * (y0 - yN));
      cpx z = Yrow[1024];
      bufB[SW(1024)] = make_float2(z.x, -z.y);
    } else {
      cpx A = Yrow[k];
      cpx M = Yrow[2048 - k];
      float Br = M.x, Bi = -M.y;
      float sr = 0.5f * (A.x + Br), si = 0.5f * (A.y + Bi);
      float dr = 0.5f * (A.x - Br), di = 0.5f * (A.y - Bi);
      float th = (float)k * (PI_F / 2048.f);
      float sn, cs; __sincosf(th, &sn, &cs);
      float e1 = cs * di + sn * dr;
      float e2 = cs * dr - sn * di;
      bufB[SW(k)] = make_float2(sr - e1, si + e2);
      bufB[SW(2048 - k)] = make_float2(sr + e1, -si + e2);
    }
  }
  __syncthreads();
  cpx a[8];
#pragma unroll
  for (int j = 0; j < 8; ++j) a[j] = bufB[SW(t + 256 * j)];
  fft2048_core<1>(a, bufA, bufB, t);
  float2* dst = (float2*)(out + (size_t)row * NL);
  const float sc = 1.f / 2048.f;
#pragma unroll
  for (int r = 0; r < 8; ++r) {
    int n = t + (r << 8);
    cpx z = bufB[SW(n)];
    dst[n] = make_float2(gelu_exact(z.x * sc), gelu_exact(z.y * sc));
  }
}

extern "C" void kernel_launch(void* const* d_in, const int* in_sizes, int n_in,
                              void* d_out, int out_size, void* d_ws, size_t ws_size,
                              hipStream_t stream) {
  const float* u   = (const float*)d_in[0];
  const float* C2  = (const float*)d_in[1];
  const float* B2  = (const float*)d_in[2];
  const float* D   = (const float*)d_in[3];
  const float* Lam = (const float*)d_in[4];
  float* out = (float*)d_out;

  const size_t PL = (size_t)128 * NT;                 // dwords per pair plane
  const size_t need = PL * 4                          // Uph
                    + PL * 8                          // Yp float2
                    + 2 * 65536 * 2 + 2 * 131072 * 2; // Mb, Mc bf16 hi/lo

  if (ws_size >= need) {
    unsigned int* Uph = (unsigned int*)d_ws;
    float2* Yp = (float2*)(Uph + PL);
    unsigned short* Mbh = (unsigned short*)(Yp + PL);
    unsigned short* Mbl = Mbh + 65536;
    unsigned short* Mch = Mbl + 65536;
    unsigned short* Mcl = Mch + 131072;

    fwd_pre<<<192 + NB * NH, 256, 0, stream>>>(u, C2, B2, D, Uph, Mbh, Mbl, Mch, Mcl);
    gemm_fused<<<256, 256, 0, stream>>>(Mbh, Mbl, Mch, Mcl, Uph, Lam, Yp);
    fft_inv_gelu_pl<<<NB * NH, 256, 0, stream>>>(Yp, out);
  } else {
    float* ws = (float*)d_ws;
    const size_t nUc = (size_t)NB * NH * LF;
    cpx* U  = (cpx*)ws;
    cpx* Yf = U;
    float* Bt = ws + 2 * nUc;
    float* Ct = Bt + 32768;
    float* Dt = Ct + 32768;
    fb_precomp<<<dim3(128, 3), 128, 0, stream>>>(C2, B2, D, Bt, Ct, Dt);
    fb_fft_fwd<<<NB * NH, 256, 0, stream>>>(u, U);
    fb_mix<<<dim3(129, NB), 256, 0, stream>>>(U, Bt, Ct, Dt, Lam, Yf);
    fb_fft_inv<<<NB * NH, 256, 0, stream>>>(Yf, out);
  }
}

// Round 4
// 122.378 us; speedup vs baseline: 1.1461x; 1.0221x over previous
//
#include <hip/hip_runtime.h>
#include <math.h>

#define PI_F 3.14159265358979323846f
#define NB 8
#define NH 128
#define NL 4096
#define LF 2049    // NL/2 + 1
#define WB 2064    // padded per-batch column width (>=2049, mult of 16)
#define NT 16512   // WB * NB = total GEMM columns

typedef float2 cpx;
typedef __attribute__((ext_vector_type(8))) short bf8v;   // 8 bf16 in 4 VGPRs
typedef __attribute__((ext_vector_type(4))) float f4;     // MFMA acc

#define MFMA16(a, b, c) __builtin_amdgcn_mfma_f32_16x16x32_bf16(a, b, c, 0, 0, 0)

__device__ __forceinline__ float gelu_exact(float x) {
  return 0.5f * x * (1.0f + erff(x * 0.70710678118654752f));
}
// Branchless erf-based GELU: Abramowitz-Stegun 7.1.26 (|err_erf| <= 1.5e-7),
// all native ops (rcp, exp), no libm call.  gelu(x) = 0.5 x (1 + erf(x/sqrt2)).
__device__ __forceinline__ float gelu_fast(float x) {
  float z = fabsf(x) * 0.70710678118654752f;
  float t = __builtin_amdgcn_rcpf(fmaf(0.3275911f, z, 1.0f));
  float p = t * fmaf(t, fmaf(t, fmaf(t, fmaf(t, 1.061405429f, -1.453152027f),
                                     1.421413741f), -0.284496736f), 0.254829592f);
  float e = __expf(-z * z);
  float er = fmaf(-p, e, 1.0f);          // erf(|x|/sqrt2)
  float s = copysignf(er, x);
  return 0.5f * x * (1.0f + s);
}
__device__ __forceinline__ unsigned short f2bf(float f) {
  unsigned int x = __float_as_uint(f);
  return (unsigned short)((x + 0x7FFFu + ((x >> 16) & 1u)) >> 16);
}
__device__ __forceinline__ float bf2f(unsigned short h) {
  return __uint_as_float((unsigned int)h << 16);
}
__device__ __forceinline__ unsigned int packpair(float re, float im) {
  return (unsigned int)f2bf(re) | ((unsigned int)f2bf(im) << 16);
}
__device__ __forceinline__ cpx cadd(cpx a, cpx b) { return make_float2(a.x + b.x, a.y + b.y); }
__device__ __forceinline__ cpx csub(cpx a, cpx b) { return make_float2(a.x - b.x, a.y - b.y); }
__device__ __forceinline__ cpx cmul(cpx a, cpx b) {
  return make_float2(fmaf(a.x, b.x, -a.y * b.y), fmaf(a.x, b.y, a.y * b.x));
}
template <int SGN>
__device__ __forceinline__ cpx mulJ(cpx a) {
  return (SGN < 0) ? make_float2(a.y, -a.x) : make_float2(-a.y, a.x);
}

// Pre-swizzled global layout for Mb/Mc: tile = k>>5 (256 rows x 32 k per tile,
// 8192 shorts), slot = m*4 + ((k>>3 & 3) ^ (m & 3)), elem = k&7.  Makes the
// GEMM A-staging a LINEAR copy (global_load_lds) with the XOR-swizzle baked
// into the source (both-sides-or-neither rule).
__device__ __forceinline__ void wrM(unsigned short* __restrict__ H,
                                    unsigned short* __restrict__ L,
                                    int m, int k, float v) {
  size_t a = (size_t)(k >> 5) * 8192 +
             (size_t)(m * 4 + (((k >> 3) & 3) ^ (m & 3))) * 8 + (k & 7);
  unsigned short h = f2bf(v);
  H[a] = h;
  L[a] = f2bf(v - bf2f(h));
}

// async global->LDS, 16B per lane; LDS dest is wave-uniform base + lane*16.
__device__ __forceinline__ void gload16(const unsigned short* g, unsigned short* l) {
  __builtin_amdgcn_global_load_lds(
      (const __attribute__((address_space(1))) unsigned int*)g,
      (__attribute__((address_space(3))) unsigned int*)l, 16, 0, 0);
}

// ---------------- register FFT-2048: radix 8*8*8*4, 256 threads ----------------
#define SW(k) ((k) ^ (((k) >> 4) & 31))

template <int SGN>
__device__ __forceinline__ void dft8(cpx a[8]) {
  cpx t0 = cadd(a[0], a[4]), u0 = csub(a[0], a[4]);
  cpx t1 = cadd(a[1], a[5]), u1 = csub(a[1], a[5]);
  cpx t2 = cadd(a[2], a[6]), u2 = csub(a[2], a[6]);
  cpx t3 = cadd(a[3], a[7]), u3 = csub(a[3], a[7]);
  cpx E0 = cadd(t0, t2), E2 = csub(t0, t2);
  cpx ju2 = mulJ<SGN>(u2);
  cpx E1 = cadd(u0, ju2), E3 = csub(u0, ju2);
  cpx O0 = cadd(t1, t3), O2 = csub(t1, t3);
  cpx ju3 = mulJ<SGN>(u3);
  cpx O1 = cadd(u1, ju3), O3 = csub(u1, ju3);
  const float r = 0.70710678118654752f;
  const float S = (float)SGN;
  cpx w1O1 = make_float2(r * (O1.x - S * O1.y), r * (O1.y + S * O1.x));
  cpx w3O3 = make_float2(r * (-O3.x - S * O3.y), r * (S * O3.x - O3.y));
  cpx jO2 = mulJ<SGN>(O2);
  a[0] = cadd(E0, O0);   a[4] = csub(E0, O0);
  a[1] = cadd(E1, w1O1); a[5] = csub(E1, w1O1);
  a[2] = cadd(E2, jO2);  a[6] = csub(E2, jO2);
  a[3] = cadd(E3, w3O3); a[7] = csub(E3, w3O3);
}

template <int SGN>
__device__ __forceinline__ void dft4(cpx b[4]) {
  cpx s0 = cadd(b[0], b[2]), d0 = csub(b[0], b[2]);
  cpx s1 = cadd(b[1], b[3]), d1 = csub(b[1], b[3]);
  cpx jd1 = mulJ<SGN>(d1);
  b[0] = cadd(s0, s1); b[2] = csub(s0, s1);
  b[1] = cadd(d0, jd1); b[3] = csub(d0, jd1);
}

__device__ __forceinline__ void twid8(cpx a[8], float ang) {
  float s, c; __sincosf(ang, &s, &c);
  cpx w1 = make_float2(c, s);
  cpx w2 = cmul(w1, w1), w3 = cmul(w2, w1), w4 = cmul(w2, w2);
  cpx w5 = cmul(w3, w2), w6 = cmul(w3, w3), w7 = cmul(w4, w3);
  a[1] = cmul(a[1], w1); a[2] = cmul(a[2], w2); a[3] = cmul(a[3], w3);
  a[4] = cmul(a[4], w4); a[5] = cmul(a[5], w5); a[6] = cmul(a[6], w6);
  a[7] = cmul(a[7], w7);
}

template <int SGN>
__device__ __forceinline__ void fft2048_core(cpx a[8], cpx* __restrict__ bufA,
                                             cpx* __restrict__ bufB, int t) {
  const float S = (float)SGN;
  dft8<SGN>(a);
  twid8(a, S * (2.f * PI_F / 2048.f) * (float)t);
#pragma unroll
  for (int p = 0; p < 8; ++p) bufA[p * 264 + t] = a[p];
  __syncthreads();
  int p = t >> 5, n1 = t & 31;
#pragma unroll
  for (int j = 0; j < 8; ++j) a[j] = bufA[p * 264 + n1 + 32 * j];
  dft8<SGN>(a);
  twid8(a, S * (2.f * PI_F / 256.f) * (float)n1);
#pragma unroll
  for (int q = 0; q < 8; ++q) bufB[p * 264 + q * 33 + n1] = a[q];
  __syncthreads();
  int q = (t >> 2) & 7, n2 = t & 3;
#pragma unroll
  for (int j = 0; j < 8; ++j) a[j] = bufB[p * 264 + q * 33 + n2 + 4 * j];
  dft8<SGN>(a);
  twid8(a, S * (2.f * PI_F / 32.f) * (float)n2);
#pragma unroll
  for (int d = 0; d < 8; ++d) bufA[p * 264 + q * 33 + 4 * d + n2] = a[d];
  __syncthreads();
#pragma unroll
  for (int h = 0; h < 2; ++h) {
    int d = 2 * n2 + h;
    cpx b[4];
#pragma unroll
    for (int m = 0; m < 4; ++m) b[m] = bufA[p * 264 + q * 33 + 4 * d + m];
    dft4<SGN>(b);
    int kb = p + 8 * q + 64 * d;
#pragma unroll
    for (int c = 0; c < 4; ++c) bufB[SW(kb + 512 * c)] = b[c];
  }
  __syncthreads();
}

// ---------------- fused: precomp (blocks 0..191) + forward rfft-4096 pack ----------------
__global__ __launch_bounds__(256) void fwd_pre(
    const float* __restrict__ u,
    const float* __restrict__ C2, const float* __restrict__ B2,
    const float* __restrict__ D,
    unsigned int* __restrict__ Uph,
    unsigned short* __restrict__ Mbh, unsigned short* __restrict__ Mbl,
    unsigned short* __restrict__ Mch, unsigned short* __restrict__ Mcl) {
  __shared__ cpx bufA[2112], bufB[2112];
  int t = threadIdx.x;
  if (blockIdx.x < 192) {
    __shared__ float rc[128], rs[128];
    __shared__ float sOr[2][128], sOi[2][128];
    __shared__ float sTr[2][128], sTi[2][128];
    int e = blockIdx.x;
    int which = e >> 6;                 // 0: Mb, 1: C~, 2: D~ (uniform per block)
    int half = t >> 7, tt = t & 127;
    int x = (2 * e + half) & 127;
    { float s, c; sincosf(-(2.f * PI_F / 128.f) * (float)tt, &s, &c); rc[tt] = c; rs[tt] = s; }
    if (which == 0) {   // stage B~ source row x: B2[x*128 + k]
      float2 v = ((const float2*)B2)[(size_t)x * 128 + tt];
      sOr[half][tt] = v.x; sOi[half][tt] = v.y;
    } else if (which == 1) {  // stage C~ source column x: C2[k*128 + x]
      float2 v = ((const float2*)C2)[(size_t)tt * 128 + x];
      sOr[half][tt] = v.x; sOi[half][tt] = v.y;
    }
    __syncthreads();
    float sr = 0.f, si = 0.f;
    if (which == 0) {
#pragma unroll 4
      for (int k = 0; k < 128; ++k) {
        int j = (k * tt) & 127; float c = rc[j], s = rs[j];
        float br = sOr[half][k], bi = sOi[half][k];
        sr += br * c - bi * s; si += br * s + bi * c;
      }
      wrM(Mbh, Mbl, 2 * x,     2 * tt,     sr);
      wrM(Mbh, Mbl, 2 * x,     2 * tt + 1, -si);
      wrM(Mbh, Mbl, 2 * x + 1, 2 * tt,     si);
      wrM(Mbh, Mbl, 2 * x + 1, 2 * tt + 1,  sr);
    } else if (which == 1) {
#pragma unroll 4
      for (int k = 0; k < 128; ++k) {
        int j = (k * tt) & 127; float c = rc[j], s = -rs[j];  // e^{+i theta}
        float cr = sOr[half][k], ci = sOi[half][k];
        sr += cr * c - ci * s; si += cr * s + ci * c;
      }
      sr *= (1.f / 128.f); si *= (1.f / 128.f);
      wrM(Mch, Mcl, 2 * tt,     2 * x,     sr);
      wrM(Mch, Mcl, 2 * tt,     2 * x + 1, -si);
      wrM(Mch, Mcl, 2 * tt + 1, 2 * x,     si);
      wrM(Mch, Mcl, 2 * tt + 1, 2 * x + 1,  sr);
    } else {
#pragma unroll 8
      for (int k = 0; k < 128; ++k) {
        int j = (k * x) & 127; float c = rc[j], s = rs[j];
        float d = D[tt * 128 + k];
        sr += d * c; si += d * s;
      }
      sTr[half][tt] = sr; sTi[half][tt] = si;
      __syncthreads();
      sr = 0.f; si = 0.f;
#pragma unroll 4
      for (int k = 0; k < 128; ++k) {
        int j = (k * tt) & 127; float c = rc[j], s = -rs[j];
        sr += sTr[half][k] * c - sTi[half][k] * s;
        si += sTr[half][k] * s + sTi[half][k] * c;
      }
      sr *= (1.f / 128.f); si *= (1.f / 128.f);
      wrM(Mch, Mcl, 2 * tt,     256 + 2 * x,     sr);
      wrM(Mch, Mcl, 2 * tt,     256 + 2 * x + 1, -si);
      wrM(Mch, Mcl, 2 * tt + 1, 256 + 2 * x,     si);
      wrM(Mch, Mcl, 2 * tt + 1, 256 + 2 * x + 1,  sr);
    }
    return;
  }
  int row = blockIdx.x - 192;
  int b = row >> 7, q = row & 127;
  const cpx* src = (const cpx*)(u + (size_t)row * NL);
  cpx a[8];
#pragma unroll
  for (int j = 0; j < 8; ++j) a[j] = src[t + 256 * j];
  fft2048_core<-1>(a, bufA, bufB, t);
  unsigned int* Uh = Uph + (size_t)q * NT + (size_t)b * WB;
  auto pstore = [&](int k, float ur, float ui) { Uh[k] = packpair(ur, ui); };
#pragma unroll
  for (int r = 0; r < 4; ++r) {
    int k = t + (r << 8);
    if (k == 0) {
      cpx z0 = bufB[SW(0)];
      pstore(0, z0.x + z0.y, 0.f);
      pstore(2048, z0.x - z0.y, 0.f);
      cpx zN = bufB[SW(1024)];
      pstore(1024, zN.x, -zN.y);
    } else {
      cpx A = bufB[SW(k)];
      cpx M = bufB[SW(2048 - k)];
      float Br = M.x, Bi = -M.y;
      float sr = 0.5f * (A.x + Br), si = 0.5f * (A.y + Bi);
      float dr = 0.5f * (A.x - Br), di = 0.5f * (A.y - Bi);
      float th = (float)k * (PI_F / 2048.f);
      float sn, cs; __sincosf(th, &sn, &cs);
      float tr = cs * dr + sn * di;
      float ti = cs * di - sn * dr;
      pstore(k, sr + ti, si - tr);
      float A2r = M.x, A2i = M.y;
      float B2r = A.x, B2i = -A.y;
      float s2r = 0.5f * (A2r + B2r), s2i = 0.5f * (A2i + B2i);
      float d2r = 0.5f * (A2r - B2r), d2i = 0.5f * (A2i - B2i);
      float t2r = -cs * d2r + sn * d2i;
      float t2i = -cs * d2i - sn * d2r;
      pstore(2048 - k, s2r + t2i, s2i - t2r);
    }
  }
}

// ---------------- fused GEMM: V = k.(Mb U), Y = Mc [V; U] ----------------
// Balanced 256-block grid: 248 blocks x 64 cols + 8 blocks x 80 cols = 16512.
// Every CU gets exactly ONE block (no serial-tail quantization).  Templated
// body over NTT (= N-tiles of 16 cols).  A: per-wave global_load_lds from
// pre-swizzled Mb/Mc, double-buffered; B: depth-3 register ring; counted
// vmcnt, never 0 mid-loop; single raw s_barrier for the V handoff.
#define VSTR 324   // Vl chunk stride in dwords (80 cols * 4 + pad)

#define VMW(n) asm volatile("s_waitcnt vmcnt(" #n ")" ::: "memory")
#define LGW()  asm volatile("s_waitcnt lgkmcnt(0)" ::: "memory")

template <int NTT>
__device__ __forceinline__ void gemm_body(
    int j0, int tid,
    unsigned short (*Ah)[8192], unsigned short (*Al)[8192], unsigned int* Vl,
    const unsigned short* __restrict__ Mbh, const unsigned short* __restrict__ Mbl,
    const unsigned short* __restrict__ Mch, const unsigned short* __restrict__ Mcl,
    const unsigned int* __restrict__ Uph,
    const float* __restrict__ Lam,
    float2* __restrict__ Yp) {
  int w = tid >> 6, lane = tid & 63, quad = lane >> 4, ln = lane & 15;

  unsigned int breg[3][NTT][4];
  f4 acc[4][NTT];

#define STAGE_A(H, L, tile, buf)                                              \
  {                                                                           \
    size_t tb_ = (size_t)(tile) * 8192;                                       \
    _Pragma("unroll") for (int r_ = 0; r_ < 4; ++r_) {                        \
      int sb_ = w * 256 + r_ * 64;                                            \
      gload16((H) + tb_ + (size_t)(sb_ + lane) * 8, &Ah[buf][sb_ * 8]);       \
      gload16((L) + tb_ + (size_t)(sb_ + lane) * 8, &Al[buf][sb_ * 8]);       \
    }                                                                         \
  }
#define LOAD_B(g, it)                                                         \
  {                                                                           \
    _Pragma("unroll") for (int nt_ = 0; nt_ < NTT; ++nt_)                     \
      _Pragma("unroll") for (int c_ = 0; c_ < 4; ++c_)                        \
        breg[g][nt_][c_] =                                                    \
            Uph[(size_t)((it) * 16 + quad * 4 + c_) * NT + j0 + nt_ * 16 + ln]; \
  }
  // vmcnt ledger: A tile = 8 gloads, B tile = 4*NTT loads per wave.
#define VMW_STEADY() { if constexpr (NTT == 4) VMW(40); else VMW(48); }
#define VMW_T1()     { if constexpr (NTT == 4) VMW(24); else VMW(28); }

  auto bFromReg = [&](int g, bf8v bh[NTT]) {
#pragma unroll
    for (int nt = 0; nt < NTT; ++nt) {
      union { unsigned int u[4]; bf8v v; } cv;
#pragma unroll
      for (int c = 0; c < 4; ++c) cv.u[c] = breg[g][nt][c];
      bh[nt] = cv.v;
    }
  };
  auto bFromV = [&](int i, bf8v bh[NTT]) {
    const unsigned short* Vs = (const unsigned short*)Vl;
#pragma unroll
    for (int nt = 0; nt < NTT; ++nt)
      bh[nt] = *(const bf8v*)&Vs[(size_t)(i * 4 + quad) * (VSTR * 2) + (nt * 16 + ln) * 8];
  };
  auto compute = [&](int buf, const bf8v* bh) {
    bf8v ah[4], al[4];
#pragma unroll
    for (int mt = 0; mt < 4; ++mt) {
      int m = w * 64 + mt * 16 + ln;
      int off = (m * 4 + (quad ^ (m & 3))) * 8;
      ah[mt] = *(const bf8v*)&Ah[buf][off];
      al[mt] = *(const bf8v*)&Al[buf][off];
    }
#pragma unroll
    for (int mt = 0; mt < 4; ++mt)
#pragma unroll
      for (int nt = 0; nt < NTT; ++nt) {
        acc[mt][nt] = MFMA16(ah[mt], bh[nt], acc[mt][nt]);
        acc[mt][nt] = MFMA16(al[mt], bh[nt], acc[mt][nt]);
      }
  };

  // ---- phase 1: V(256 x 16*NTT) = Mb x U ----
  STAGE_A(Mbh, Mbl, 0, 0);
  LOAD_B(0, 0);
  LOAD_B(1, 1);
#pragma unroll
  for (int mt = 0; mt < 4; ++mt)
#pragma unroll
    for (int nt = 0; nt < NTT; ++nt) acc[mt][nt] = (f4){0.f, 0.f, 0.f, 0.f};

#pragma unroll
  for (int i = 0; i < 6; ++i) {
    LGW();
    STAGE_A(Mbh, Mbl, i + 1, (i + 1) & 1);
    LOAD_B((i + 2) % 3, i + 2);
    VMW_STEADY();
    bf8v bh[NTT]; bFromReg(i % 3, bh); compute(i & 1, bh);
  }
  { // i = 6
    LGW(); STAGE_A(Mbh, Mbl, 7, 1); VMW_T1();
    bf8v bh[NTT]; bFromReg(0, bh); compute(0, bh);
  }
  { // i = 7: also prefetch phase-2 A tile 0 into slot 0
    LGW(); STAGE_A(Mch, Mcl, 0, 0); VMW(8);
    bf8v bh[NTT]; bFromReg(1, bh); compute(1, bh);
  }

  // phase-1 epilogue: Cauchy scale, V -> LDS
#pragma unroll
  for (int mt = 0; mt < 4; ++mt) {
    int r0 = w * 64 + mt * 16 + quad * 4;
    int p0 = r0 >> 1;   // even
    float2 lam0 = ((const float2*)Lam)[p0];
    float2 lam1 = ((const float2*)Lam)[p0 + 1];
#pragma unroll
    for (int nt = 0; nt < NTT; ++nt) {
      int col = nt * 16 + ln;
      int gcol = j0 + col;
      int bb = gcol / WB; int l = gcol - bb * WB;
      float omega = (float)l * (PI_F / 2048.f);
      f4 a = acc[mt][nt];
      float dx0 = -lam0.x, dy0 = omega - lam0.y;
      float inv0 = 1.f / (dx0 * dx0 + dy0 * dy0);
      float kr0 = dx0 * inv0, ki0 = -dy0 * inv0;
      float v0r = kr0 * a[0] - ki0 * a[1];
      float v0i = kr0 * a[1] + ki0 * a[0];
      float dx1 = -lam1.x, dy1 = omega - lam1.y;
      float inv1 = 1.f / (dx1 * dx1 + dy1 * dy1);
      float kr1 = dx1 * inv1, ki1 = -dy1 * inv1;
      float v1r = kr1 * a[2] - ki1 * a[3];
      float v1i = kr1 * a[3] + ki1 * a[2];
      int ch = p0 >> 2;
      Vl[ch * VSTR + col * 4 + (p0 & 3)] = packpair(v0r, v0i);
      Vl[ch * VSTR + col * 4 + ((p0 + 1) & 3)] = packpair(v1r, v1i);
    }
  }
  LGW();                              // Vl ds_writes complete -> visible
  __builtin_amdgcn_s_barrier();       // raw barrier: does NOT drain the A prefetch

  // ---- phase 2: Y(256 x 16*NTT) = Mc x [V; U] ----
#pragma unroll
  for (int mt = 0; mt < 4; ++mt)
#pragma unroll
    for (int nt = 0; nt < NTT; ++nt) acc[mt][nt] = (f4){0.f, 0.f, 0.f, 0.f};

#pragma unroll
  for (int i = 0; i < 6; ++i) {            // k in [0,192): B = V from LDS
    LGW();
    STAGE_A(Mch, Mcl, i + 1, (i + 1) & 1);
    VMW(8);
    bf8v bh[NTT]; bFromV(i, bh); compute(i & 1, bh);
  }
  { // i = 6: start U prefetch for iters 8..15
    LGW(); STAGE_A(Mch, Mcl, 7, 1); LOAD_B(2, 0); VMW_T1();
    bf8v bh[NTT]; bFromV(6, bh); compute(0, bh);
  }
  { // i = 7
    LGW(); STAGE_A(Mch, Mcl, 8, 0); LOAD_B(0, 1); VMW_STEADY();
    bf8v bh[NTT]; bFromV(7, bh); compute(1, bh);
  }
#pragma unroll
  for (int i = 8; i < 14; ++i) {           // k in [256,448): B = U from registers
    LGW();
    STAGE_A(Mch, Mcl, i + 1, (i + 1) & 1);
    LOAD_B((i + 2) % 3, i + 2 - 8);
    VMW_STEADY();
    bf8v bh[NTT]; bFromReg(i % 3, bh); compute(i & 1, bh);
  }
  { // i = 14
    LGW(); STAGE_A(Mch, Mcl, 15, 1); VMW_T1();
    bf8v bh[NTT]; bFromReg(2, bh); compute(0, bh);
  }
  { // i = 15
    LGW(); VMW(0);
    bf8v bh[NTT]; bFromReg(0, bh); compute(1, bh);
  }

#pragma unroll
  for (int mt = 0; mt < 4; ++mt) {
    int r0 = w * 64 + mt * 16 + quad * 4;
    int h0 = r0 >> 1;   // even
#pragma unroll
    for (int nt = 0; nt < NTT; ++nt) {
      int gcol = j0 + nt * 16 + ln;
      f4 a = acc[mt][nt];
      Yp[(size_t)h0 * NT + gcol] = make_float2(a[0], a[1]);
      Yp[(size_t)(h0 + 1) * NT + gcol] = make_float2(a[2], a[3]);
    }
  }
#undef STAGE_A
#undef LOAD_B
#undef VMW_STEADY
#undef VMW_T1
}

__global__ __launch_bounds__(256, 1) void gemm_fused(
    const unsigned short* __restrict__ Mbh, const unsigned short* __restrict__ Mbl,
    const unsigned short* __restrict__ Mch, const unsigned short* __restrict__ Mcl,
    const unsigned int* __restrict__ Uph,
    const float* __restrict__ Lam,
    float2* __restrict__ Yp) {
  __shared__ unsigned short Ah[2][8192], Al[2][8192];  // 64 KB, slot-swizzled
  __shared__ unsigned int Vl[32 * VSTR];               // 41.5 KB
  int tid = threadIdx.x;
  int bid = blockIdx.x;
  if (bid < 248) {
    gemm_body<4>(bid * 64, tid, Ah, Al, Vl, Mbh, Mbl, Mch, Mcl, Uph, Lam, Yp);
  } else {
    gemm_body<5>(248 * 64 + (bid - 248) * 80, tid, Ah, Al, Vl, Mbh, Mbl, Mch, Mcl, Uph, Lam, Yp);
  }
}

// ---------------- inverse rfft-4096 from float2 pair planes, fused fast-exact GELU ----------------
__global__ __launch_bounds__(256) void fft_inv_gelu_pl(const float2* __restrict__ Yp,
                                                       float* __restrict__ out) {
  __shared__ cpx bufA[2112], bufB[2112];
  int t = threadIdx.x;
  int row = blockIdx.x;
  int b = row >> 7, h = row & 127;
  const float2* Yrow = Yp + (size_t)h * NT + (size_t)b * WB;
#pragma unroll
  for (int r = 0; r < 4; ++r) {
    int k = t + (r << 8);
    if (k == 0) {
      float y0 = Yrow[0].x;     // Im discarded (pocketfft irfft semantics)
      float yN = Yrow[2048].x;
      bufB[SW(0)] = make_float2(0.5f * (y0 + yN), 0.5f * (y0 - yN));
      float2 z = Yrow[1024];
      bufB[SW(1024)] = make_float2(z.x, -z.y);
    } else {
      float2 A = Yrow[k];
      float2 M = Yrow[2048 - k];
      float Br = M.x, Bi = -M.y;
      float sr = 0.5f * (A.x + Br), si = 0.5f * (A.y + Bi);
      float dr = 0.5f * (A.x - Br), di = 0.5f * (A.y - Bi);
      float th = (float)k * (PI_F / 2048.f);
      float sn, cs; __sincosf(th, &sn, &cs);
      float e1 = cs * di + sn * dr;
      float e2 = cs * dr - sn * di;
      bufB[SW(k)] = make_float2(sr - e1, si + e2);
      bufB[SW(2048 - k)] = make_float2(sr + e1, -si + e2);
    }
  }
  __syncthreads();
  cpx a[8];
#pragma unroll
  for (int j = 0; j < 8; ++j) a[j] = bufB[SW(t + 256 * j)];
  fft2048_core<1>(a, bufA, bufB, t);
  float2* dst = (float2*)(out + (size_t)row * NL);
  const float sc = 1.f / 2048.f;
#pragma unroll
  for (int r = 0; r < 8; ++r) {
    int n = t + (r << 8);
    cpx z = bufB[SW(n)];
    dst[n] = make_float2(gelu_fast(z.x * sc), gelu_fast(z.y * sc));
  }
}

// ================= FALLBACK (fp32 path, used only if ws too small) =================
__global__ __launch_bounds__(128) void fb_precomp(
    const float* __restrict__ C2, const float* __restrict__ B2,
    const float* __restrict__ D,
    float* __restrict__ Bt, float* __restrict__ Ct, float* __restrict__ Dt) {
  __shared__ float rc[128], rs[128];
  __shared__ float sTr[128], sTi[128];
  int x = blockIdx.x, t = threadIdx.x, which = blockIdx.y;
  { float s, c; sincosf(-(2.f * PI_F / 128.f) * (float)t, &s, &c); rc[t] = c; rs[t] = s; }
  __syncthreads();
  float sr = 0.f, si = 0.f;
  if (which == 0) {
    for (int k = 0; k < 128; ++k) {
      int j = (k * t) & 127; float c = rc[j], s = rs[j];
      float br = B2[(x * 128 + k) * 2], bi = B2[(x * 128 + k) * 2 + 1];
      sr += br * c - bi * s; si += br * s + bi * c;
    }
    Bt[(t * 128 + x) * 2] = sr; Bt[(t * 128 + x) * 2 + 1] = si;
  } else if (which == 1) {
    for (int k = 0; k < 128; ++k) {
      int j = (k * t) & 127; float c = rc[j], s = -rs[j];
      float cr = C2[(k * 128 + x) * 2], ci = C2[(k * 128 + x) * 2 + 1];
      sr += cr * c - ci * s; si += cr * s + ci * c;
    }
    Ct[(x * 128 + t) * 2] = sr * (1.f / 128.f);
    Ct[(x * 128 + t) * 2 + 1] = si * (1.f / 128.f);
  } else {
    for (int k = 0; k < 128; ++k) {
      int j = (k * x) & 127; float c = rc[j], s = rs[j];
      float d = D[t * 128 + k];
      sr += d * c; si += d * s;
    }
    sTr[t] = sr; sTi[t] = si;
    __syncthreads();
    sr = 0.f; si = 0.f;
    for (int k = 0; k < 128; ++k) {
      int j = (k * t) & 127; float c = rc[j], s = -rs[j];
      sr += sTr[k] * c - sTi[k] * s;
      si += sTr[k] * s + sTi[k] * c;
    }
    Dt[(x * 128 + t) * 2] = sr * (1.f / 128.f);
    Dt[(x * 128 + t) * 2 + 1] = si * (1.f / 128.f);
  }
}

__global__ __launch_bounds__(256) void fb_fft_fwd(const float* __restrict__ u,
                                                  cpx* __restrict__ U) {
  __shared__ cpx bufA[2112], bufB[2112];
  int t = threadIdx.x;
  int row = blockIdx.x;
  const cpx* src = (const cpx*)(u + (size_t)row * NL);
  cpx a[8];
#pragma unroll
  for (int j = 0; j < 8; ++j) a[j] = src[t + 256 * j];
  fft2048_core<-1>(a, bufA, bufB, t);
  cpx* Urow = U + (size_t)row * LF;
#pragma unroll
  for (int r = 0; r < 4; ++r) {
    int k = t + (r << 8);
    if (k == 0) {
      cpx z0 = bufB[SW(0)];
      Urow[0] = make_float2(z0.x + z0.y, 0.f);
      Urow[2048] = make_float2(z0.x - z0.y, 0.f);
      cpx zN = bufB[SW(1024)];
      Urow[1024] = make_float2(zN.x, -zN.y);
    } else {
      cpx A = bufB[SW(k)];
      cpx M = bufB[SW(2048 - k)];
      float Br = M.x, Bi = -M.y;
      float sr = 0.5f * (A.x + Br), si = 0.5f * (A.y + Bi);
      float dr = 0.5f * (A.x - Br), di = 0.5f * (A.y - Bi);
      float th = (float)k * (PI_F / 2048.f);
      float sn, cs; __sincosf(th, &sn, &cs);
      float tr = cs * dr + sn * di;
      float ti = cs * di - sn * dr;
      Urow[k] = make_float2(sr + ti, si - tr);
      float A2r = M.x, A2i = M.y;
      float B2r = A.x, B2i = -A.y;
      float s2r = 0.5f * (A2r + B2r), s2i = 0.5f * (A2i + B2i);
      float d2r = 0.5f * (A2r - B2r), d2i = 0.5f * (A2i - B2i);
      float t2r = -cs * d2r + sn * d2i;
      float t2i = -cs * d2i - sn * d2r;
      Urow[2048 - k] = make_float2(s2r + t2i, s2i - t2r);
    }
  }
}

__device__ __forceinline__ void ld4(float4 d[4], const float4* __restrict__ p) {
#pragma unroll
  for (int kk = 0; kk < 4; ++kk) d[kk] = p[kk];
}
__device__ __forceinline__ void cmac4(const float4 m[4], float xr, float xi,
                                      float ar[8], float ai[8]) {
#pragma unroll
  for (int kk = 0; kk < 4; ++kk) {
    float4 v = m[kk];
    ar[2 * kk]     = fmaf(v.x, xr, fmaf(-v.y, xi, ar[2 * kk]));
    ai[2 * kk]     = fmaf(v.x, xi, fmaf( v.y, xr, ai[2 * kk]));
    ar[2 * kk + 1] = fmaf(v.z, xr, fmaf(-v.w, xi, ar[2 * kk + 1]));
    ai[2 * kk + 1] = fmaf(v.z, xi, fmaf( v.w, xr, ai[2 * kk + 1]));
  }
}

__global__ __launch_bounds__(256) void fb_mix(
    const cpx* __restrict__ U,
    const float* __restrict__ Bt, const float* __restrict__ Ct,
    const float* __restrict__ Dt, const float* __restrict__ Lam,
    cpx* __restrict__ Y) {
  __shared__ cpx sU[128][17], sV[128][17];
  int tid = threadIdx.x;
  int b = blockIdx.y;
  size_t ub = (size_t)b * NH * LF;
  if (blockIdx.x == 128) {
    int t = tid;
    if (t < 128) sU[t][0] = U[ub + (size_t)t * LF + 2048];
    __syncthreads();
    if (t < 128) {
      float ar = 0.f, ai = 0.f;
      for (int q = 0; q < 128; ++q) {
        float ur = sU[q][0].x, ui = sU[q][0].y;
        float br = Bt[(q * 128 + t) * 2], bi = Bt[(q * 128 + t) * 2 + 1];
        ar = fmaf(br, ur, fmaf(-bi, ui, ar));
        ai = fmaf(br, ui, fmaf(bi, ur, ai));
      }
      float a = Lam[2 * t], bb = Lam[2 * t + 1];
      float dx = -a, dy = PI_F - bb;
      float inv = 1.f / (dx * dx + dy * dy);
      float kr = dx * inv, ki = -dy * inv;
      sV[t][0] = make_float2(kr * ar - ki * ai, kr * ai + ki * ar);
    }
    __syncthreads();
    if (t < 128) {
      float ar = 0.f, ai = 0.f;
      for (int q = 0; q < 128; ++q) {
        float ur = sU[q][0].x, ui = sU[q][0].y;
        float vr = sV[q][0].x, vi = sV[q][0].y;
        float cr = Ct[(q * 128 + t) * 2], ci = Ct[(q * 128 + t) * 2 + 1];
        float dr = Dt[(q * 128 + t) * 2], di = Dt[(q * 128 + t) * 2 + 1];
        ar += cr * vr - ci * vi + dr * ur - di * ui;
        ai += cr * vi + ci * vr + dr * ui + di * ur;
      }
      Y[ub + (size_t)t * LF + 2048] = make_float2(ar, ai);
    }
    return;
  }
  int lane = tid & 15, g = tid >> 4;
  int l = blockIdx.x * 16 + lane;
#pragma unroll
  for (int rep = 0; rep < 8; ++rep) {
    int q = rep * 16 + g;
    sU[q][lane] = U[ub + (size_t)q * LF + l];
  }
  __syncthreads();
  float omega = (float)l * (PI_F / 2048.f);
  float ar[8], ai[8];
  {
#pragma unroll
    for (int k = 0; k < 8; ++k) { ar[k] = 0.f; ai[k] = 0.f; }
    const float4* base = (const float4*)Bt + g * 4;
    float4 e[4], o[4];
    ld4(e, base);
#pragma unroll 1
    for (int q = 0; q < 128; q += 2) {
      ld4(o, base + (q + 1) * 64);
      cpx u0 = sU[q][lane];
      cmac4(e, u0.x, u0.y, ar, ai);
      ld4(e, base + ((q + 2) & 127) * 64);
      cpx u1 = sU[q + 1][lane];
      cmac4(o, u1.x, u1.y, ar, ai);
    }
    int p0 = g * 8;
#pragma unroll
    for (int k = 0; k < 8; ++k) {
      int p = p0 + k;
      float a = Lam[2 * p], bb = Lam[2 * p + 1];
      float dx = -a, dy = omega - bb;
      float inv = 1.f / (dx * dx + dy * dy);
      float kr = dx * inv, ki = -dy * inv;
      sV[p][lane] = make_float2(kr * ar[k] - ki * ai[k], kr * ai[k] + ki * ar[k]);
    }
  }
  __syncthreads();
  {
#pragma unroll
    for (int k = 0; k < 8; ++k) { ar[k] = 0.f; ai[k] = 0.f; }
    const float4* base = (const float4*)Ct + g * 4;
    float4 e[4], o[4];
    ld4(e, base);
#pragma unroll 1
    for (int q = 0; q < 128; q += 2) {
      ld4(o, base + (q + 1) * 64);
      cpx v0 = sV[q][lane];
      cmac4(e, v0.x, v0.y, ar, ai);
      ld4(e, base + ((q + 2) & 127) * 64);
      cpx v1 = sV[q + 1][lane];
      cmac4(o, v1.x, v1.y, ar, ai);
    }
  }
  {
    const float4* base = (const float4*)Dt + g * 4;
    float4 e[4], o[4];
    ld4(e, base);
#pragma unroll 1
    for (int q = 0; q < 128; q += 2) {
      ld4(o, base + (q + 1) * 64);
      cpx u0 = sU[q][lane];
      cmac4(e, u0.x, u0.y, ar, ai);
      ld4(e, base + ((q + 2) & 127) * 64);
      cpx u1 = sU[q + 1][lane];
      cmac4(o, u1.x, u1.y, ar, ai);
    }
  }
  int h0 = g * 8;
#pragma unroll
  for (int k = 0; k < 8; ++k) {
    Y[ub + (size_t)(h0 + k) * LF + l] = make_float2(ar[k], ai[k]);
  }
}

__global__ __launch_bounds__(256) void fb_fft_inv(const cpx* __restrict__ Y,
                                                  float* __restrict__ out) {
  __shared__ cpx bufA[2112], bufB[2112];
  int t = threadIdx.x;
  int row = blockIdx.x;
  const cpx* Yrow = Y + (size_t)row * LF;
#pragma unroll
  for (int r = 0; r < 4; ++r) {
    int k = t + (r << 8);
    if (k == 0) {
      float y0 = Yrow[0].x;
      float yN = Yrow[2048].x;
      bufB[SW(0)] = make_float2(0.5f * (y0 + yN), 0.5f * (y0 - yN));
      cpx z = Yrow[1024];
      bufB[SW(1024)] = make_float2(z.x, -z.y);
    } else {
      cpx A = Yrow[k];
      cpx M = Yrow[2048 - k];
      float Br = M.x, Bi = -M.y;
      float sr = 0.5f * (A.x + Br), si = 0.5f * (A.y + Bi);
      float dr = 0.5f * (A.x - Br), di = 0.5f * (A.y - Bi);
      float th = (float)k * (PI_F / 2048.f);
      float sn, cs; __sincosf(th, &sn, &cs);
      float e1 = cs * di + sn * dr;
      float e2 = cs * dr - sn * di;
      bufB[SW(k)] = make_float2(sr - e1, si + e2);
      bufB[SW(2048 - k)] = make_float2(sr + e1, -si + e2);
    }
  }
  __syncthreads();
  cpx a[8];
#pragma unroll
  for (int j = 0; j < 8; ++j) a[j] = bufB[SW(t + 256 * j)];
  fft2048_core<1>(a, bufA, bufB, t);
  float2* dst = (float2*)(out + (size_t)row * NL);
  const float sc = 1.f / 2048.f;
#pragma unroll
  for (int r = 0; r < 8; ++r) {
    int n = t + (r << 8);
    cpx z = bufB[SW(n)];
    dst[n] = make_float2(gelu_exact(z.x * sc), gelu_exact(z.y * sc));
  }
}

extern "C" void kernel_launch(void* const* d_in, const int* in_sizes, int n_in,
                              void* d_out, int out_size, void* d_ws, size_t ws_size,
                              hipStream_t stream) {
  const float* u   = (const float*)d_in[0];
  const float* C2  = (const float*)d_in[1];
  const float* B2  = (const float*)d_in[2];
  const float* D   = (const float*)d_in[3];
  const float* Lam = (const float*)d_in[4];
  float* out = (float*)d_out;

  const size_t PL = (size_t)128 * NT;                 // dwords per pair plane
  const size_t need = PL * 4                          // Uph
                    + PL * 8                          // Yp float2
                    + 2 * 65536 * 2 + 2 * 131072 * 2; // Mb, Mc bf16 hi/lo

  if (ws_size >= need) {
    unsigned int* Uph = (unsigned int*)d_ws;
    float2* Yp = (float2*)(Uph + PL);
    unsigned short* Mbh = (unsigned short*)(Yp + PL);
    unsigned short* Mbl = Mbh + 65536;
    unsigned short* Mch = Mbl + 65536;
    unsigned short* Mcl = Mch + 131072;

    fwd_pre<<<192 + NB * NH, 256, 0, stream>>>(u, C2, B2, D, Uph, Mbh, Mbl, Mch, Mcl);
    gemm_fused<<<256, 256, 0, stream>>>(Mbh, Mbl, Mch, Mcl, Uph, Lam, Yp);
    fft_inv_gelu_pl<<<NB * NH, 256, 0, stream>>>(Yp, out);
  } else {
    float* ws = (float*)d_ws;
    const size_t nUc = (size_t)NB * NH * LF;
    cpx* U  = (cpx*)ws;
    cpx* Yf = U;
    float* Bt = ws + 2 * nUc;
    float* Ct = Bt + 32768;
    float* Dt = Ct + 32768;
    fb_precomp<<<dim3(128, 3), 128, 0, stream>>>(C2, B2, D, Bt, Ct, Dt);
    fb_fft_fwd<<<NB * NH, 256, 0, stream>>>(u, U);
    fb_mix<<<dim3(129, NB), 256, 0, stream>>>(U, Bt, Ct, Dt, Lam, Yf);
    fb_fft_inv<<<NB * NH, 256, 0, stream>>>(Yf, out);
  }
}